// Round 2
// baseline (841.555 us; speedup 1.0000x reference)
//
#include <hip/hip_runtime.h>
#include <math.h>

// B=8, C=512, L=1024, heads=8x64, GROUPS=32, cond Lc=77 D=768. fp32 in/out.
// GEMMs run as bf16x3-split MFMA (Wh*Xh + Wh*Xl + Wl*Xh), error ~3e-5 rel.
// Attention / LN / kvc remain fp32 (next optimization target once counters exist).

typedef float f32x4 __attribute__((ext_vector_type(4)));
typedef short s16x8 __attribute__((ext_vector_type(8)));
typedef unsigned short ushort_t;

__device__ __forceinline__ float gelu_exact(float v) {
    return 0.5f * v * (1.0f + erff(v * 0.70710678118654752f));
}
__device__ __forceinline__ ushort_t f2bf(float f) {
    unsigned int u = __float_as_uint(f);
    return (ushort_t)((u + 0x7FFFu + ((u >> 16) & 1u)) >> 16);
}
__device__ __forceinline__ float bf2f(ushort_t h) {
    return __uint_as_float(((unsigned int)h) << 16);
}

// ================================================================
// GroupNorm stats -> per-(b,c) scale/bias (fused into consumer convert pass).
__global__ __launch_bounds__(256) void gn_stats_k(
    const float* __restrict__ x, const float* __restrict__ gw,
    const float* __restrict__ gb, float* __restrict__ oscl, float* __restrict__ obia)
{
    const int blk = blockIdx.x;
    const int b = blk >> 5, g = blk & 31;
    const float4* base = (const float4*)(x + ((size_t)b * 512 + (size_t)g * 16) * 1024);
    float s = 0.f, sq = 0.f;
    for (int i = threadIdx.x; i < 4096; i += 256) {
        float4 v = base[i];
        s  += v.x + v.y + v.z + v.w;
        sq += v.x * v.x + v.y * v.y + v.z * v.z + v.w * v.w;
    }
#pragma unroll
    for (int m = 32; m >= 1; m >>= 1) { s += __shfl_xor(s, m); sq += __shfl_xor(sq, m); }
    __shared__ float ls[4], lq[4];
    const int wid = threadIdx.x >> 6;
    if ((threadIdx.x & 63) == 0) { ls[wid] = s; lq[wid] = sq; }
    __syncthreads();
    if (threadIdx.x == 0) {
        float S = ls[0] + ls[1] + ls[2] + ls[3];
        float Q = lq[0] + lq[1] + lq[2] + lq[3];
        float mean = S * (1.f / 16384.f);
        float var  = Q * (1.f / 16384.f) - mean * mean;
        float istd = rsqrtf(var + 1e-5f);
#pragma unroll
        for (int cc = 0; cc < 16; cc++) {
            int c = g * 16 + cc;
            float sc = gw[c] * istd;
            oscl[b * 512 + c] = sc;
            obia[b * 512 + c] = gb[c] - mean * sc;
        }
    }
}

// ================================================================
// LayerNorm over D=768, writes transposed cn_t[b, d, t].
__global__ __launch_bounds__(256) void ln_t_k(
    const float* __restrict__ cond, const float* __restrict__ lw,
    const float* __restrict__ lb, float* __restrict__ out)
{
    const int blk = blockIdx.x;
    const int b = blk / 77, t = blk % 77;
    const float* row = cond + ((size_t)b * 77 + t) * 768;
    float v[3];
    float s = 0.f, sq = 0.f;
#pragma unroll
    for (int p = 0; p < 3; p++) {
        v[p] = row[threadIdx.x + p * 256];
        s += v[p]; sq += v[p] * v[p];
    }
#pragma unroll
    for (int m = 32; m >= 1; m >>= 1) { s += __shfl_xor(s, m); sq += __shfl_xor(sq, m); }
    __shared__ float ls[4], lq[4], stat[2];
    const int wid = threadIdx.x >> 6;
    if ((threadIdx.x & 63) == 0) { ls[wid] = s; lq[wid] = sq; }
    __syncthreads();
    if (threadIdx.x == 0) {
        float S = ls[0] + ls[1] + ls[2] + ls[3];
        float Q = lq[0] + lq[1] + lq[2] + lq[3];
        float mean = S * (1.f / 768.f);
        float var  = Q * (1.f / 768.f) - mean * mean;
        stat[0] = mean; stat[1] = rsqrtf(var + 1e-5f);
    }
    __syncthreads();
    const float mean = stat[0], istd = stat[1];
#pragma unroll
    for (int p = 0; p < 3; p++) {
        int d = threadIdx.x + p * 256;
        out[((size_t)b * 768 + d) * 77 + t] = (v[p] - mean) * istd * lw[d] + lb[d];
    }
}

// ================================================================
// Weight split: fp32 -> (hi, lo) bf16, elementwise.
__global__ __launch_bounds__(256) void wsplit_k(
    const float* __restrict__ w, ushort_t* __restrict__ oh, ushort_t* __restrict__ ol, int n4)
{
    for (int i = blockIdx.x * 256 + threadIdx.x; i < n4; i += gridDim.x * 256) {
        float4 v = ((const float4*)w)[i];
        ushort4 h, l;
        h.x = f2bf(v.x); l.x = f2bf(v.x - bf2f(h.x));
        h.y = f2bf(v.y); l.y = f2bf(v.y - bf2f(h.y));
        h.z = f2bf(v.z); l.z = f2bf(v.z - bf2f(h.z));
        h.w = f2bf(v.w); l.w = f2bf(v.w - bf2f(h.w));
        ((ushort4*)oh)[i] = h;
        ((ushort4*)ol)[i] = l;
    }
}

// ================================================================
// Transpose + split (+ optional per-(b,row) scale/bias = fused GroupNorm):
// in fp32 [b][R][C] -> out (hi,lo) bf16 [b][C][R]. R,C multiples of 64.
template<bool SB>
__global__ __launch_bounds__(256) void tsplit_k(
    const float* __restrict__ in, const float* __restrict__ scl,
    const float* __restrict__ bia, ushort_t* __restrict__ oh,
    ushort_t* __restrict__ ol, int R, int C)
{
    __shared__ ushort_t Lh[64][68], Ll[64][68];
    const int b = blockIdx.z, r0 = blockIdx.y * 64, c0 = blockIdx.x * 64;
    const int tid = threadIdx.x;
#pragma unroll
    for (int p = 0; p < 4; p++) {
        const int q = tid + p * 256;
        const int rr = q >> 4, cc4 = (q & 15) * 4;
        float4 v = *(const float4*)(in + ((size_t)b * R + r0 + rr) * C + c0 + cc4);
        if (SB) {
            const float s = scl[b * R + r0 + rr], o = bia[b * R + r0 + rr];
            v.x = v.x * s + o; v.y = v.y * s + o; v.z = v.z * s + o; v.w = v.w * s + o;
        }
        ushort4 h, l;
        h.x = f2bf(v.x); l.x = f2bf(v.x - bf2f(h.x));
        h.y = f2bf(v.y); l.y = f2bf(v.y - bf2f(h.y));
        h.z = f2bf(v.z); l.z = f2bf(v.z - bf2f(h.z));
        h.w = f2bf(v.w); l.w = f2bf(v.w - bf2f(h.w));
        *(ushort4*)&Lh[rr][cc4] = h;
        *(ushort4*)&Ll[rr][cc4] = l;
    }
    __syncthreads();
#pragma unroll
    for (int p = 0; p < 4; p++) {
        const int q = tid + p * 256;
        const int nn = q >> 4, rr4 = (q & 15) * 4;
        ushort4 h, l;
        h.x = Lh[rr4 + 0][nn]; h.y = Lh[rr4 + 1][nn];
        h.z = Lh[rr4 + 2][nn]; h.w = Lh[rr4 + 3][nn];
        l.x = Ll[rr4 + 0][nn]; l.y = Ll[rr4 + 1][nn];
        l.z = Ll[rr4 + 2][nn]; l.w = Ll[rr4 + 3][nn];
        *(ushort4*)(oh + ((size_t)b * C + c0 + nn) * R + r0 + rr4) = h;
        *(ushort4*)(ol + ((size_t)b * C + c0 + nn) * R + r0 + rr4) = l;
    }
}

// ================================================================
// MFMA GEMM (bf16x3): out[b][m][n] = sum_k W[m][k] X[k][n] + bias[m].
// W as (Wh,Wl) bf16 [M][K]; X as (Xh,Xl) bf16 TRANSPOSED [b][N][K].
// Tile 128x128xBK64, 4 waves, each 64x64 out (4x4 frags of 16x16x32 MFMA).
// LDS [row][64] bf16 with XOR swizzle byte^=((row&7)<<4) on write AND read
// -> ds_read_b128 frag reads are ~conflict-free (G4 / T2).
// MODE: 0 = +bias; 1 = +bias+res (fp32 out); 2 = +bias+gelu, out transposed
// (hi,lo) bf16 [b][N][M] (feeds the next GEMM directly).
template<int MODE>
__global__ __launch_bounds__(256, 2) void mgemm_k(
    const ushort_t* __restrict__ Wh, const ushort_t* __restrict__ Wl,
    const ushort_t* __restrict__ Xh, const ushort_t* __restrict__ Xl,
    const float* __restrict__ bias, const float* __restrict__ res,
    float* __restrict__ out, ushort_t* __restrict__ outh, ushort_t* __restrict__ outl,
    int M, int K, int N)
{
    __shared__ __align__(16) char smem[65536];
    char* As_h = smem;
    char* As_l = smem + 16384;
    char* Bs_h = smem + 32768;
    char* Bs_l = smem + 49152;

    const int b  = blockIdx.z;
    const int bm = blockIdx.y * 128, bn = blockIdx.x * 128;
    const int tid = threadIdx.x;

    // staging addressing: chunk c = tid + p*256; row = c>>3, 16B chunk (c&7)
    const int srow  = tid >> 3;            // +p*32
    const int ke    = (tid & 7) * 8;       // element offset within 64-elem row slice
    const int sswz  = ((tid & 7) * 16) ^ (((tid >> 3) & 7) << 4);

    const ushort_t* Wph = Wh + (size_t)(bm + srow) * K + ke;
    const ushort_t* Wpl = Wl + (size_t)(bm + srow) * K + ke;
    const ushort_t* Xph = Xh + ((size_t)b * N + bn + srow) * K + ke;
    const ushort_t* Xpl = Xl + ((size_t)b * N + bn + srow) * K + ke;

    // fragment addressing
    const int l    = tid & 63, w = tid >> 6;
    const int wm   = (w >> 1) * 64, wn = (w & 1) * 64;
    const int lrow = l & 15, lk = l >> 4;
    const int fswz = (l & 7) << 4;
    const int akb0 = (lk * 16) ^ fswz;
    const int akb1 = (64 + lk * 16) ^ fswz;
    const int abase = (wm + lrow) * 128;
    const int bbase = (wn + lrow) * 128;

    f32x4 acc[4][4];
    const f32x4 zf = {0.f, 0.f, 0.f, 0.f};
#pragma unroll
    for (int i = 0; i < 4; i++)
#pragma unroll
        for (int j = 0; j < 4; j++) acc[i][j] = zf;

    for (int k0 = 0; k0 < K; k0 += 64) {
#pragma unroll
        for (int p = 0; p < 4; p++) {
            const int row = srow + p * 32;
            const int loff = row * 128 + sswz;
            s16x8 a = *(const s16x8*)(Wph + (size_t)(p * 32) * K + k0);
            s16x8 c = *(const s16x8*)(Wpl + (size_t)(p * 32) * K + k0);
            s16x8 d = *(const s16x8*)(Xph + (size_t)(p * 32) * K + k0);
            s16x8 e = *(const s16x8*)(Xpl + (size_t)(p * 32) * K + k0);
            *(s16x8*)(As_h + loff) = a;
            *(s16x8*)(As_l + loff) = c;
            *(s16x8*)(Bs_h + loff) = d;
            *(s16x8*)(Bs_l + loff) = e;
        }
        __syncthreads();
#pragma unroll
        for (int kk = 0; kk < 2; kk++) {
            const int akb = kk ? akb1 : akb0;
            s16x8 ah[4], al[4];
#pragma unroll
            for (int mf = 0; mf < 4; mf++) {
                ah[mf] = *(const s16x8*)(As_h + abase + mf * 2048 + akb);
                al[mf] = *(const s16x8*)(As_l + abase + mf * 2048 + akb);
            }
#pragma unroll
            for (int nf = 0; nf < 4; nf++) {
                s16x8 bh = *(const s16x8*)(Bs_h + bbase + nf * 2048 + akb);
                s16x8 bl = *(const s16x8*)(Bs_l + bbase + nf * 2048 + akb);
#pragma unroll
                for (int mf = 0; mf < 4; mf++) {
                    acc[mf][nf] = __builtin_amdgcn_mfma_f32_16x16x32_bf16(ah[mf], bh, acc[mf][nf], 0, 0, 0);
                    acc[mf][nf] = __builtin_amdgcn_mfma_f32_16x16x32_bf16(ah[mf], bl, acc[mf][nf], 0, 0, 0);
                    acc[mf][nf] = __builtin_amdgcn_mfma_f32_16x16x32_bf16(al[mf], bh, acc[mf][nf], 0, 0, 0);
                }
            }
        }
        __syncthreads();
    }

    // epilogue. C/D layout: col = lane&15, row = (lane>>4)*4 + reg  [m89]
    const int mb = bm + wm, nb = bn + wn;
    float bs[4][4];
#pragma unroll
    for (int mf = 0; mf < 4; mf++)
#pragma unroll
        for (int r = 0; r < 4; r++) bs[mf][r] = bias[mb + mf * 16 + lk * 4 + r];

    if (MODE == 2) {
#pragma unroll
        for (int mf = 0; mf < 4; mf++) {
            const int m0 = mb + mf * 16 + lk * 4;
#pragma unroll
            for (int nf = 0; nf < 4; nf++) {
                const int n = nb + nf * 16 + lrow;
                ushort4 hv, lv;
#pragma unroll
                for (int r = 0; r < 4; r++) {
                    float v = acc[mf][nf][r] + bs[mf][r];
                    v = gelu_exact(v);
                    ushort_t h = f2bf(v);
                    ushort_t lo = f2bf(v - bf2f(h));
                    if (r == 0) { hv.x = h; lv.x = lo; }
                    else if (r == 1) { hv.y = h; lv.y = lo; }
                    else if (r == 2) { hv.z = h; lv.z = lo; }
                    else { hv.w = h; lv.w = lo; }
                }
                *(ushort4*)(outh + ((size_t)b * N + n) * M + m0) = hv;
                *(ushort4*)(outl + ((size_t)b * N + n) * M + m0) = lv;
            }
        }
    } else {
        const size_t obase = (size_t)b * (size_t)M * N;
#pragma unroll
        for (int mf = 0; mf < 4; mf++)
#pragma unroll
            for (int r = 0; r < 4; r++) {
                const int m = mb + mf * 16 + lk * 4 + r;
                const size_t rowo = obase + (size_t)m * N;
#pragma unroll
                for (int nf = 0; nf < 4; nf++) {
                    const int n = nb + nf * 16 + lrow;
                    float v = acc[mf][nf][r] + bs[mf][r];
                    if (MODE == 1) v += res[rowo + n];
                    out[rowo + n] = v;
                }
            }
    }
}

// ================================================================
// Small fp32 GEMM for kvc (M=1024, K=768, N=77).
__global__ __launch_bounds__(256, 2) void gemm_small_k(
    const float* __restrict__ W, const float* __restrict__ X,
    const float* __restrict__ bias, float* __restrict__ out,
    int M, int K, int N)
{
    __shared__ float Ws[16][32];
    __shared__ float Xs[16][128];
    const int b  = blockIdx.z;
    const int bm = blockIdx.y * 32;
    const float* Wp = W + (size_t)bm * K;
    const float* Xp = X + (size_t)b * K * N;
    const int tid = threadIdx.x, tx = tid & 15, ty = tid >> 4;
    const int xr = tid >> 5, xc = (tid & 31) * 4;
    float acc[2][8];
#pragma unroll
    for (int i = 0; i < 2; i++)
#pragma unroll
        for (int j = 0; j < 8; j++) acc[i][j] = 0.f;

    for (int k0 = 0; k0 < K; k0 += 16) {
        {
            const int idx = tid * 2;
            const int r = idx >> 4, kk = idx & 15;
            float2 w2 = *(const float2*)(Wp + (size_t)r * K + k0 + kk);
            Ws[kk][r] = w2.x; Ws[kk + 1][r] = w2.y;
        }
#pragma unroll
        for (int p = 0; p < 2; p++) {
            const int kr = xr + p * 8;
            const float* xrow = Xp + (size_t)(k0 + kr) * N;
            float4 v;
            v.x = (xc + 0 < N) ? xrow[xc + 0] : 0.f;
            v.y = (xc + 1 < N) ? xrow[xc + 1] : 0.f;
            v.z = (xc + 2 < N) ? xrow[xc + 2] : 0.f;
            v.w = (xc + 3 < N) ? xrow[xc + 3] : 0.f;
            *(float4*)&Xs[kr][xc] = v;
        }
        __syncthreads();
#pragma unroll
        for (int kk = 0; kk < 16; kk++) {
            const float a0 = Ws[kk][ty * 2], a1 = Ws[kk][ty * 2 + 1];
            float bb[8];
            *(float4*)&bb[0] = *(const float4*)&Xs[kk][tx * 8];
            *(float4*)&bb[4] = *(const float4*)&Xs[kk][tx * 8 + 4];
#pragma unroll
            for (int j = 0; j < 8; j++) {
                acc[0][j] = fmaf(a0, bb[j], acc[0][j]);
                acc[1][j] = fmaf(a1, bb[j], acc[1][j]);
            }
        }
        __syncthreads();
    }
    const size_t obase = (size_t)b * (size_t)M * N;
#pragma unroll
    for (int i = 0; i < 2; i++) {
        const int m = bm + ty * 2 + i;
        const float bvv = bias[m];
#pragma unroll
        for (int j = 0; j < 8; j++) {
            const int n = tx * 8 + j;
            if (n < N) out[obase + (size_t)m * N + n] = acc[i][j] + bvv;
        }
    }
}

// ================================================================
// Flash-style fp32 attention (unchanged from baseline). Self: slen=1024,
// stride 1024. Cross: slen=77, stride 77, int mask, accumulate into Ob.
__global__ __launch_bounds__(256, 2) void attn_k(
    const float* __restrict__ Qb, const float* __restrict__ Kb,
    const float* __restrict__ Vb, float* __restrict__ Ob,
    const int* __restrict__ mask, int slen, int srs,
    size_t q_bs, size_t kv_bs, int accum)
{
    __shared__ float Qs[64][64];
    __shared__ float Ks[64][64];
    __shared__ float Ps[64][65];
    __shared__ float Vs[64][68];
    const int b = blockIdx.z, h = blockIdx.y, tt = blockIdx.x;
    const int tid = threadIdx.x, tx = tid & 15, ty = tid >> 4;
    const float* qp = Qb + (size_t)b * q_bs + (size_t)(h * 64) * 1024 + (size_t)tt * 64;
    const float* kp = Kb + (size_t)b * kv_bs + (size_t)(h * 64) * srs;
    const float* vp = Vb + (size_t)b * kv_bs + (size_t)(h * 64) * srs;
    {
        const int c0 = tid >> 4, t4 = (tid & 15) * 4;
#pragma unroll
        for (int p = 0; p < 4; p++) {
            const int c = c0 + p * 16;
            *(float4*)&Qs[c][t4] = *(const float4*)(qp + (size_t)c * 1024 + t4);
        }
    }
    float O[4][4] = {};
    float mo[4], lo[4];
#pragma unroll
    for (int i = 0; i < 4; i++) { mo[i] = -INFINITY; lo[i] = 0.f; }

    const int nst = (slen + 63) >> 6;
    for (int st = 0; st < nst; st++) {
        const int s0 = st * 64;
        {
            const int c0 = tid >> 4, s4 = (tid & 15) * 4;
            if (srs == 1024) {
#pragma unroll
                for (int p = 0; p < 4; p++) {
                    const int c = c0 + p * 16;
                    float4 k4 = *(const float4*)(kp + (size_t)c * 1024 + s0 + s4);
                    *(float4*)&Ks[c][s4] = k4;
                    float4 v4 = *(const float4*)(vp + (size_t)c * 1024 + s0 + s4);
                    Vs[s4 + 0][c] = v4.x; Vs[s4 + 1][c] = v4.y;
                    Vs[s4 + 2][c] = v4.z; Vs[s4 + 3][c] = v4.w;
                }
            } else {
#pragma unroll
                for (int p = 0; p < 4; p++) {
                    const int c = c0 + p * 16;
#pragma unroll
                    for (int u = 0; u < 4; u++) {
                        const int s = s0 + s4 + u;
                        const bool ok = (s < slen);
                        Ks[c][s4 + u] = ok ? kp[(size_t)c * srs + s] : 0.f;
                        Vs[s4 + u][c] = ok ? vp[(size_t)c * srs + s] : 0.f;
                    }
                }
            }
        }
        __syncthreads();
        float Sv[4][4] = {};
#pragma unroll 16
        for (int c = 0; c < 64; c++) {
            float qa[4], kb4[4];
            *(float4*)qa  = *(const float4*)&Qs[c][ty * 4];
            *(float4*)kb4 = *(const float4*)&Ks[c][tx * 4];
#pragma unroll
            for (int i = 0; i < 4; i++)
#pragma unroll
                for (int j = 0; j < 4; j++)
                    Sv[i][j] = fmaf(qa[i], kb4[j], Sv[i][j]);
        }
        float alpha[4];
#pragma unroll
        for (int i = 0; i < 4; i++) {
#pragma unroll
            for (int j = 0; j < 4; j++) {
                const int s = s0 + tx * 4 + j;
                const float sv = Sv[i][j] * 0.125f;
                const bool valid = (s < slen) && (mask == nullptr || mask[b * slen + s] != 0);
                Sv[i][j] = valid ? sv : -INFINITY;
            }
            float rm = fmaxf(fmaxf(Sv[i][0], Sv[i][1]), fmaxf(Sv[i][2], Sv[i][3]));
#pragma unroll
            for (int m = 1; m < 16; m <<= 1) rm = fmaxf(rm, __shfl_xor(rm, m));
            const float mn = fmaxf(mo[i], rm);
            alpha[i] = (mo[i] == -INFINITY) ? 0.f : expf(mo[i] - mn);
            float rs = 0.f;
#pragma unroll
            for (int j = 0; j < 4; j++) {
                const float p = (Sv[i][j] == -INFINITY) ? 0.f : expf(Sv[i][j] - mn);
                Sv[i][j] = p; rs += p;
            }
#pragma unroll
            for (int m = 1; m < 16; m <<= 1) rs += __shfl_xor(rs, m);
            lo[i] = lo[i] * alpha[i] + rs;
            mo[i] = mn;
#pragma unroll
            for (int j = 0; j < 4; j++) Ps[ty * 4 + i][tx * 4 + j] = Sv[i][j];
        }
        __syncthreads();
#pragma unroll
        for (int i = 0; i < 4; i++)
#pragma unroll
            for (int j = 0; j < 4; j++) O[i][j] *= alpha[i];
#pragma unroll 16
        for (int s = 0; s < 64; s++) {
            float va[4], pa[4];
            *(float4*)va = *(const float4*)&Vs[s][tx * 4];
#pragma unroll
            for (int i = 0; i < 4; i++) pa[i] = Ps[ty * 4 + i][s];
#pragma unroll
            for (int i = 0; i < 4; i++)
#pragma unroll
                for (int j = 0; j < 4; j++)
                    O[i][j] = fmaf(pa[i], va[j], O[i][j]);
        }
        __syncthreads();
    }
    float rl[4];
#pragma unroll
    for (int i = 0; i < 4; i++) rl[i] = (lo[i] > 0.f) ? 1.f / lo[i] : 0.f;
#pragma unroll
    for (int i = 0; i < 4; i++)
#pragma unroll
        for (int j = 0; j < 4; j++)
            Ps[tx * 4 + j][ty * 4 + i] = O[i][j] * rl[i];
    __syncthreads();
    {
        const int c0 = tid >> 4, t4 = (tid & 15) * 4;
#pragma unroll
        for (int p = 0; p < 4; p++) {
            const int c = c0 + p * 16;
            float4 v;
            v.x = Ps[c][t4 + 0]; v.y = Ps[c][t4 + 1];
            v.z = Ps[c][t4 + 2]; v.w = Ps[c][t4 + 3];
            const size_t ga = ((size_t)b * 512 + (size_t)(h * 64 + c)) * 1024
                            + (size_t)tt * 64 + t4;
            if (accum) {
                float4 o = *(const float4*)&Ob[ga];
                v.x += o.x; v.y += o.y; v.z += o.z; v.w += o.w;
            }
            *(float4*)&Ob[ga] = v;
        }
    }
}

// ================================================================
extern "C" void kernel_launch(void* const* d_in, const int* in_sizes, int n_in,
                              void* d_out, int out_size, void* d_ws, size_t ws_size,
                              hipStream_t stream) {
    (void)in_sizes; (void)n_in; (void)out_size; (void)ws_size;
    const float* x        = (const float*)d_in[0];
    const float* cond     = (const float*)d_in[1];
    const int*   cmask    = (const int*)  d_in[2];
    const float* gn_w     = (const float*)d_in[3];
    const float* gn_b     = (const float*)d_in[4];
    const float* qkv_w    = (const float*)d_in[5];
    const float* qkv_b    = (const float*)d_in[6];
    const float* ln_w     = (const float*)d_in[7];
    const float* ln_b     = (const float*)d_in[8];
    const float* kvc_w    = (const float*)d_in[9];
    const float* kvc_b    = (const float*)d_in[10];
    const float* proj_w   = (const float*)d_in[11];
    const float* proj_b   = (const float*)d_in[12];
    const float* ffn_gn_w = (const float*)d_in[13];
    const float* ffn_gn_b = (const float*)d_in[14];
    const float* ffn_w1   = (const float*)d_in[15];
    const float* ffn_b1   = (const float*)d_in[16];
    const float* ffn_w2   = (const float*)d_in[17];
    const float* ffn_b2   = (const float*)d_in[18];

    // Workspace layout (float units). Total 29,431,808 floats ~= 112.3 MiB.
    float* ws    = (float*)d_ws;
    float* gn1_s = ws;                       //    4096
    float* gn1_b = ws + 4096;
    float* gn2_s = ws + 8192;
    float* gn2_b = ws + 12288;
    float* cnt   = ws + 16384;               //  473088  cn_t [8][768][77]
    float* kvc   = ws + 489472;              //  630784  [8][1024][77]
    float* x1    = ws + 1120256;             // 4194304  [8][512][1024]
    float* qkv   = ws + 5314560;             // 12582912 [8][1536][1024]
    float* hb    = qkv + 12582912;           // 4194304  [8][512][1024]
    // yt pair overlays qkv+hb (both dead by ffn1): 2 x 16,777,216 ushort
    ushort_t* yt_h = (ushort_t*)qkv;
    ushort_t* yt_l = yt_h + 16777216;
    // transposed-split activation slot (xt1 -> ht -> x1t, sequential lifetimes)
    ushort_t* ts_h = (ushort_t*)(ws + 22091776); // 4,194,304 ushort each
    ushort_t* ts_l = ts_h + 4194304;
    // split weights
    ushort_t* wq_h = (ushort_t*)(ws + 26286080);
    ushort_t* wq_l = wq_h + 786432;
    ushort_t* wp_h = wq_l + 786432;
    ushort_t* wp_l = wp_h + 262144;
    ushort_t* w1_h = wp_l + 262144;
    ushort_t* w1_l = w1_h + 1048576;
    ushort_t* w2_h = w1_l + 1048576;
    ushort_t* w2_l = w2_h + 1048576;

    // 1) GN1 stats
    gn_stats_k<<<256, 256, 0, stream>>>(x, gn_w, gn_b, gn1_s, gn1_b);
    // 2) split weights
    wsplit_k<<<768, 256, 0, stream>>>(qkv_w, wq_h, wq_l, 196608);
    wsplit_k<<<256, 256, 0, stream>>>(proj_w, wp_h, wp_l, 65536);
    wsplit_k<<<1024, 256, 0, stream>>>(ffn_w1, w1_h, w1_l, 262144);
    wsplit_k<<<1024, 256, 0, stream>>>(ffn_w2, w2_h, w2_l, 262144);
    // 3) xt1 = T(GN1(x)) split  [8][1024][512]
    tsplit_k<true><<<dim3(16, 8, 8), 256, 0, stream>>>(x, gn1_s, gn1_b, ts_h, ts_l, 512, 1024);
    // 4) qkv = qkv_w @ GN1(x) + b   [1536,512,1024]
    mgemm_k<0><<<dim3(8, 12, 8), 256, 0, stream>>>(
        wq_h, wq_l, ts_h, ts_l, qkv_b, nullptr, qkv, nullptr, nullptr, 1536, 512, 1024);
    // 5) self-attention -> hb
    attn_k<<<dim3(16, 8, 8), 256, 0, stream>>>(
        qkv, qkv + (size_t)512 * 1024, qkv + (size_t)1024 * 1024, hb,
        nullptr, 1024, 1024, (size_t)1536 * 1024, (size_t)1536 * 1024, 0);
    // 6) LayerNorm(cond) transposed; kvc = kvc_w @ cn_t + b
    ln_t_k<<<616, 256, 0, stream>>>(cond, ln_w, ln_b, cnt);
    gemm_small_k<<<dim3(1, 32, 8), 256, 0, stream>>>(kvc_w, cnt, kvc_b, kvc, 1024, 768, 77);
    // 7) cross-attention, accumulate into hb
    attn_k<<<dim3(16, 8, 8), 256, 0, stream>>>(
        qkv, kvc, kvc + (size_t)512 * 77, hb,
        cmask, 77, 77, (size_t)1536 * 1024, (size_t)1024 * 77, 1);
    // 8) ht = T(hb) split
    tsplit_k<false><<<dim3(16, 8, 8), 256, 0, stream>>>(hb, nullptr, nullptr, ts_h, ts_l, 512, 1024);
    // 9) x1 = x + proj_w @ hb + b   [512,512,1024]
    mgemm_k<1><<<dim3(8, 4, 8), 256, 0, stream>>>(
        wp_h, wp_l, ts_h, ts_l, proj_b, x, x1, nullptr, nullptr, 512, 512, 1024);
    // 10) GN2 stats on x1
    gn_stats_k<<<256, 256, 0, stream>>>(x1, ffn_gn_w, ffn_gn_b, gn2_s, gn2_b);
    // 11) x1t = T(GN2(x1)) split
    tsplit_k<true><<<dim3(16, 8, 8), 256, 0, stream>>>(x1, gn2_s, gn2_b, ts_h, ts_l, 512, 1024);
    // 12) ffn1: y = gelu(w1 @ GN2(x1) + b1), emitted transposed-split -> yt
    mgemm_k<2><<<dim3(8, 16, 8), 256, 0, stream>>>(
        w1_h, w1_l, ts_h, ts_l, ffn_b1, nullptr, nullptr, yt_h, yt_l, 2048, 512, 1024);
    // 13) out = x1 + w2 @ y + b2    [512,2048,1024]
    mgemm_k<1><<<dim3(8, 4, 8), 256, 0, stream>>>(
        w2_h, w2_l, yt_h, yt_l, ffn_b2, x1, (float*)d_out, nullptr, nullptr, 512, 2048, 1024);
}

// Round 5
// 548.139 us; speedup vs baseline: 1.5353x; 1.5353x over previous
//
#include <hip/hip_runtime.h>
#include <math.h>

// B=8, C=512, L=1024, heads=8x64, GROUPS=32, cond Lc=77 D=768. fp32 in/out.
// GEMMs: bf16x3-split MFMA. Attention: plain-bf16 MFMA flash.

typedef float f32x4 __attribute__((ext_vector_type(4)));
typedef short s16x8 __attribute__((ext_vector_type(8)));
typedef unsigned short ushort_t;

__device__ __forceinline__ float gelu_exact(float v) {
    return 0.5f * v * (1.0f + erff(v * 0.70710678118654752f));
}
__device__ __forceinline__ ushort_t f2bf(float f) {
    unsigned int u = __float_as_uint(f);
    return (ushort_t)((u + 0x7FFFu + ((u >> 16) & 1u)) >> 16);
}
__device__ __forceinline__ float bf2f(ushort_t h) {
    return __uint_as_float(((unsigned int)h) << 16);
}

// ================================================================
__global__ __launch_bounds__(256) void gn_stats_k(
    const float* __restrict__ x, const float* __restrict__ gw,
    const float* __restrict__ gb, float* __restrict__ oscl, float* __restrict__ obia)
{
    const int blk = blockIdx.x;
    const int b = blk >> 5, g = blk & 31;
    const float4* base = (const float4*)(x + ((size_t)b * 512 + (size_t)g * 16) * 1024);
    float s = 0.f, sq = 0.f;
    for (int i = threadIdx.x; i < 4096; i += 256) {
        float4 v = base[i];
        s  += v.x + v.y + v.z + v.w;
        sq += v.x * v.x + v.y * v.y + v.z * v.z + v.w * v.w;
    }
#pragma unroll
    for (int m = 32; m >= 1; m >>= 1) { s += __shfl_xor(s, m); sq += __shfl_xor(sq, m); }
    __shared__ float ls[4], lq[4];
    const int wid = threadIdx.x >> 6;
    if ((threadIdx.x & 63) == 0) { ls[wid] = s; lq[wid] = sq; }
    __syncthreads();
    if (threadIdx.x == 0) {
        float S = ls[0] + ls[1] + ls[2] + ls[3];
        float Q = lq[0] + lq[1] + lq[2] + lq[3];
        float mean = S * (1.f / 16384.f);
        float var  = Q * (1.f / 16384.f) - mean * mean;
        float istd = rsqrtf(var + 1e-5f);
#pragma unroll
        for (int cc = 0; cc < 16; cc++) {
            int c = g * 16 + cc;
            float sc = gw[c] * istd;
            oscl[b * 512 + c] = sc;
            obia[b * 512 + c] = gb[c] - mean * sc;
        }
    }
}

// ================================================================
__global__ __launch_bounds__(256) void ln_t_k(
    const float* __restrict__ cond, const float* __restrict__ lw,
    const float* __restrict__ lb, float* __restrict__ out)
{
    const int blk = blockIdx.x;
    const int b = blk / 77, t = blk % 77;
    const float* row = cond + ((size_t)b * 77 + t) * 768;
    float v[3];
    float s = 0.f, sq = 0.f;
#pragma unroll
    for (int p = 0; p < 3; p++) {
        v[p] = row[threadIdx.x + p * 256];
        s += v[p]; sq += v[p] * v[p];
    }
#pragma unroll
    for (int m = 32; m >= 1; m >>= 1) { s += __shfl_xor(s, m); sq += __shfl_xor(sq, m); }
    __shared__ float ls[4], lq[4], stat[2];
    const int wid = threadIdx.x >> 6;
    if ((threadIdx.x & 63) == 0) { ls[wid] = s; lq[wid] = sq; }
    __syncthreads();
    if (threadIdx.x == 0) {
        float S = ls[0] + ls[1] + ls[2] + ls[3];
        float Q = lq[0] + lq[1] + lq[2] + lq[3];
        float mean = S * (1.f / 768.f);
        float var  = Q * (1.f / 768.f) - mean * mean;
        stat[0] = mean; stat[1] = rsqrtf(var + 1e-5f);
    }
    __syncthreads();
    const float mean = stat[0], istd = stat[1];
#pragma unroll
    for (int p = 0; p < 3; p++) {
        int d = threadIdx.x + p * 256;
        out[((size_t)b * 768 + d) * 77 + t] = (v[p] - mean) * istd * lw[d] + lb[d];
    }
}

// ================================================================
// fp32 -> (hi, lo) bf16 split, elementwise (weights and hb).
__global__ __launch_bounds__(256) void wsplit_k(
    const float* __restrict__ w, ushort_t* __restrict__ oh, ushort_t* __restrict__ ol, int n4)
{
    for (int i = blockIdx.x * 256 + threadIdx.x; i < n4; i += gridDim.x * 256) {
        float4 v = ((const float4*)w)[i];
        ushort4 h, l;
        h.x = f2bf(v.x); l.x = f2bf(v.x - bf2f(h.x));
        h.y = f2bf(v.y); l.y = f2bf(v.y - bf2f(h.y));
        h.z = f2bf(v.z); l.z = f2bf(v.z - bf2f(h.z));
        h.w = f2bf(v.w); l.w = f2bf(v.w - bf2f(h.w));
        ((ushort4*)oh)[i] = h;
        ((ushort4*)ol)[i] = l;
    }
}

// ================================================================
// Transpose + split (+ optional fused GN scale/bias): [b][R][C] -> [b][C][R].
template<bool SB>
__global__ __launch_bounds__(256) void tsplit_k(
    const float* __restrict__ in, const float* __restrict__ scl,
    const float* __restrict__ bia, ushort_t* __restrict__ oh,
    ushort_t* __restrict__ ol, int R, int C)
{
    __shared__ ushort_t Lh[64][68], Ll[64][68];
    const int b = blockIdx.z, r0 = blockIdx.y * 64, c0 = blockIdx.x * 64;
    const int tid = threadIdx.x;
#pragma unroll
    for (int p = 0; p < 4; p++) {
        const int q = tid + p * 256;
        const int rr = q >> 4, cc4 = (q & 15) * 4;
        float4 v = *(const float4*)(in + ((size_t)b * R + r0 + rr) * C + c0 + cc4);
        if (SB) {
            const float s = scl[b * R + r0 + rr], o = bia[b * R + r0 + rr];
            v.x = v.x * s + o; v.y = v.y * s + o; v.z = v.z * s + o; v.w = v.w * s + o;
        }
        ushort4 h, l;
        h.x = f2bf(v.x); l.x = f2bf(v.x - bf2f(h.x));
        h.y = f2bf(v.y); l.y = f2bf(v.y - bf2f(h.y));
        h.z = f2bf(v.z); l.z = f2bf(v.z - bf2f(h.z));
        h.w = f2bf(v.w); l.w = f2bf(v.w - bf2f(h.w));
        *(ushort4*)&Lh[rr][cc4] = h;
        *(ushort4*)&Ll[rr][cc4] = l;
    }
    __syncthreads();
#pragma unroll
    for (int p = 0; p < 4; p++) {
        const int q = tid + p * 256;
        const int nn = q >> 4, rr4 = (q & 15) * 4;
        ushort4 h, l;
        h.x = Lh[rr4 + 0][nn]; h.y = Lh[rr4 + 1][nn];
        h.z = Lh[rr4 + 2][nn]; h.w = Lh[rr4 + 3][nn];
        l.x = Ll[rr4 + 0][nn]; l.y = Ll[rr4 + 1][nn];
        l.z = Ll[rr4 + 2][nn]; l.w = Ll[rr4 + 3][nn];
        *(ushort4*)(oh + ((size_t)b * C + c0 + nn) * R + r0 + rr4) = h;
        *(ushort4*)(ol + ((size_t)b * C + c0 + nn) * R + r0 + rr4) = l;
    }
}

// ================================================================
// MFMA GEMM (bf16x3). W (hi,lo) [M][K]; X (hi,lo) transposed [b][N][K].
// 128x128xBK64, 4 waves, 64x64/wave, swizzled LDS (verified round-1).
// MODE 1: +bias+res, fp32 out [b][M][N].
// MODE 2: +bias+gelu, out transposed (hi,lo) bf16 [b][N][M].
// MODE 3: +bias, *0.35355339 (attn scale), out transposed bf16 [b][N][512]:
//         rows m<512 -> buffer outh (qt), rows >=512 -> outl (kt), col m%512.
// MODE 4: +bias, out plain bf16 [b][M][N] (v for attention).
template<int MODE>
__global__ __launch_bounds__(256, 2) void mgemm_k(
    const ushort_t* __restrict__ Wh, const ushort_t* __restrict__ Wl,
    const ushort_t* __restrict__ Xh, const ushort_t* __restrict__ Xl,
    const float* __restrict__ bias, const float* __restrict__ res,
    float* __restrict__ out, ushort_t* __restrict__ outh, ushort_t* __restrict__ outl,
    int M, int K, int N)
{
    __shared__ __align__(16) char smem[65536];
    char* As_h = smem;
    char* As_l = smem + 16384;
    char* Bs_h = smem + 32768;
    char* Bs_l = smem + 49152;

    const int b  = blockIdx.z;
    const int bm = blockIdx.y * 128, bn = blockIdx.x * 128;
    const int tid = threadIdx.x;

    const int srow  = tid >> 3;
    const int ke    = (tid & 7) * 8;
    const int sswz  = ((tid & 7) * 16) ^ (((tid >> 3) & 7) << 4);

    const ushort_t* Wph = Wh + (size_t)(bm + srow) * K + ke;
    const ushort_t* Wpl = Wl + (size_t)(bm + srow) * K + ke;
    const ushort_t* Xph = Xh + ((size_t)b * N + bn + srow) * K + ke;
    const ushort_t* Xpl = Xl + ((size_t)b * N + bn + srow) * K + ke;

    const int l    = tid & 63, w = tid >> 6;
    const int wm   = (w >> 1) * 64, wn = (w & 1) * 64;
    const int lrow = l & 15, lk = l >> 4;
    const int fswz = (l & 7) << 4;
    const int akb0 = (lk * 16) ^ fswz;
    const int akb1 = (64 + lk * 16) ^ fswz;
    const int abase = (wm + lrow) * 128;
    const int bbase = (wn + lrow) * 128;

    f32x4 acc[4][4];
    const f32x4 zf = {0.f, 0.f, 0.f, 0.f};
#pragma unroll
    for (int i = 0; i < 4; i++)
#pragma unroll
        for (int j = 0; j < 4; j++) acc[i][j] = zf;

    for (int k0 = 0; k0 < K; k0 += 64) {
#pragma unroll
        for (int p = 0; p < 4; p++) {
            const int row = srow + p * 32;
            const int loff = row * 128 + sswz;
            s16x8 a = *(const s16x8*)(Wph + (size_t)(p * 32) * K + k0);
            s16x8 c = *(const s16x8*)(Wpl + (size_t)(p * 32) * K + k0);
            s16x8 d = *(const s16x8*)(Xph + (size_t)(p * 32) * K + k0);
            s16x8 e = *(const s16x8*)(Xpl + (size_t)(p * 32) * K + k0);
            *(s16x8*)(As_h + loff) = a;
            *(s16x8*)(As_l + loff) = c;
            *(s16x8*)(Bs_h + loff) = d;
            *(s16x8*)(Bs_l + loff) = e;
        }
        __syncthreads();
#pragma unroll
        for (int kk = 0; kk < 2; kk++) {
            const int akb = kk ? akb1 : akb0;
            s16x8 ah[4], al[4];
#pragma unroll
            for (int mf = 0; mf < 4; mf++) {
                ah[mf] = *(const s16x8*)(As_h + abase + mf * 2048 + akb);
                al[mf] = *(const s16x8*)(As_l + abase + mf * 2048 + akb);
            }
#pragma unroll
            for (int nf = 0; nf < 4; nf++) {
                s16x8 bh = *(const s16x8*)(Bs_h + bbase + nf * 2048 + akb);
                s16x8 bl = *(const s16x8*)(Bs_l + bbase + nf * 2048 + akb);
#pragma unroll
                for (int mf = 0; mf < 4; mf++) {
                    acc[mf][nf] = __builtin_amdgcn_mfma_f32_16x16x32_bf16(ah[mf], bh, acc[mf][nf], 0, 0, 0);
                    acc[mf][nf] = __builtin_amdgcn_mfma_f32_16x16x32_bf16(ah[mf], bl, acc[mf][nf], 0, 0, 0);
                    acc[mf][nf] = __builtin_amdgcn_mfma_f32_16x16x32_bf16(al[mf], bh, acc[mf][nf], 0, 0, 0);
                }
            }
        }
        __syncthreads();
    }

    // epilogue. C/D: col = lane&15 (n), row = (lane>>4)*4 + reg (m)  [m89]
    const int mb = bm + wm, nb = bn + wn;
    float bs[4][4];
#pragma unroll
    for (int mf = 0; mf < 4; mf++)
#pragma unroll
        for (int r = 0; r < 4; r++) bs[mf][r] = bias[mb + mf * 16 + lk * 4 + r];

    if (MODE == 2) {
#pragma unroll
        for (int mf = 0; mf < 4; mf++) {
            const int m0 = mb + mf * 16 + lk * 4;
#pragma unroll
            for (int nf = 0; nf < 4; nf++) {
                const int n = nb + nf * 16 + lrow;
                ushort4 hv, lv;
#pragma unroll
                for (int r = 0; r < 4; r++) {
                    float v = acc[mf][nf][r] + bs[mf][r];
                    v = gelu_exact(v);
                    ushort_t h = f2bf(v);
                    ushort_t lo = f2bf(v - bf2f(h));
                    if (r == 0) { hv.x = h; lv.x = lo; }
                    else if (r == 1) { hv.y = h; lv.y = lo; }
                    else if (r == 2) { hv.z = h; lv.z = lo; }
                    else { hv.w = h; lv.w = lo; }
                }
                *(ushort4*)(outh + ((size_t)b * N + n) * M + m0) = hv;
                *(ushort4*)(outl + ((size_t)b * N + n) * M + m0) = lv;
            }
        }
    } else if (MODE == 3) {
        const float scl = 0.35355339059327373f;
        ushort_t* dstb = (bm < 512) ? outh : outl;
        const int mloc = (bm < 512) ? mb : mb - 512;
#pragma unroll
        for (int mf = 0; mf < 4; mf++) {
            const int m0 = mloc + mf * 16 + lk * 4;
#pragma unroll
            for (int nf = 0; nf < 4; nf++) {
                const int n = nb + nf * 16 + lrow;
                ushort4 hv;
#pragma unroll
                for (int r = 0; r < 4; r++) {
                    float v = (acc[mf][nf][r] + bs[mf][r]) * scl;
                    if (r == 0) hv.x = f2bf(v);
                    else if (r == 1) hv.y = f2bf(v);
                    else if (r == 2) hv.z = f2bf(v);
                    else hv.w = f2bf(v);
                }
                *(ushort4*)(dstb + ((size_t)b * 1024 + n) * 512 + m0) = hv;
            }
        }
    } else if (MODE == 4) {
#pragma unroll
        for (int mf = 0; mf < 4; mf++)
#pragma unroll
            for (int r = 0; r < 4; r++) {
                const int m = mb + mf * 16 + lk * 4 + r;
#pragma unroll
                for (int nf = 0; nf < 4; nf++) {
                    const int n = nb + nf * 16 + lrow;
                    outh[((size_t)b * 512 + m) * 1024 + n] = f2bf(acc[mf][nf][r] + bs[mf][r]);
                }
            }
    } else {
        const size_t obase = (size_t)b * (size_t)M * N;
#pragma unroll
        for (int mf = 0; mf < 4; mf++)
#pragma unroll
            for (int r = 0; r < 4; r++) {
                const int m = mb + mf * 16 + lk * 4 + r;
                const size_t rowo = obase + (size_t)m * N;
#pragma unroll
                for (int nf = 0; nf < 4; nf++) {
                    const int n = nb + nf * 16 + lrow;
                    float v = acc[mf][nf][r] + bs[mf][r];
                    if (MODE == 1) v += res[rowo + n];
                    out[rowo + n] = v;
                }
            }
    }
}

// ================================================================
// kvc GEMM (M=1024, K=768, N=77 padded to 128). fp32 compute; epilogue emits
// kct bf16 [b][128][512] (transposed, *scale, zero-pad) and vcn bf16
// [b][512][128] (zero-pad).
__global__ __launch_bounds__(256, 2) void gemm_small_k(
    const float* __restrict__ W, const float* __restrict__ X,
    const float* __restrict__ bias, ushort_t* __restrict__ kct,
    ushort_t* __restrict__ vcn, int M, int K, int N)
{
    __shared__ float Ws[16][32];
    __shared__ float Xs[16][128];
    const int b  = blockIdx.z;
    const int bm = blockIdx.y * 32;
    const float* Wp = W + (size_t)bm * K;
    const float* Xp = X + (size_t)b * K * N;
    const int tid = threadIdx.x, tx = tid & 15, ty = tid >> 4;
    const int xr = tid >> 5, xc = (tid & 31) * 4;
    float acc[2][8];
#pragma unroll
    for (int i = 0; i < 2; i++)
#pragma unroll
        for (int j = 0; j < 8; j++) acc[i][j] = 0.f;

    for (int k0 = 0; k0 < K; k0 += 16) {
        {
            const int idx = tid * 2;
            const int r = idx >> 4, kk = idx & 15;
            float2 w2 = *(const float2*)(Wp + (size_t)r * K + k0 + kk);
            Ws[kk][r] = w2.x; Ws[kk + 1][r] = w2.y;
        }
#pragma unroll
        for (int p = 0; p < 2; p++) {
            const int kr = xr + p * 8;
            const float* xrow = Xp + (size_t)(k0 + kr) * N;
            float4 v;
            v.x = (xc + 0 < N) ? xrow[xc + 0] : 0.f;
            v.y = (xc + 1 < N) ? xrow[xc + 1] : 0.f;
            v.z = (xc + 2 < N) ? xrow[xc + 2] : 0.f;
            v.w = (xc + 3 < N) ? xrow[xc + 3] : 0.f;
            *(float4*)&Xs[kr][xc] = v;
        }
        __syncthreads();
#pragma unroll
        for (int kk = 0; kk < 16; kk++) {
            const float a0 = Ws[kk][ty * 2], a1 = Ws[kk][ty * 2 + 1];
            float bb[8];
            *(float4*)&bb[0] = *(const float4*)&Xs[kk][tx * 8];
            *(float4*)&bb[4] = *(const float4*)&Xs[kk][tx * 8 + 4];
#pragma unroll
            for (int j = 0; j < 8; j++) {
                acc[0][j] = fmaf(a0, bb[j], acc[0][j]);
                acc[1][j] = fmaf(a1, bb[j], acc[1][j]);
            }
        }
        __syncthreads();
    }
    const float scl = 0.35355339059327373f;
#pragma unroll
    for (int i = 0; i < 2; i++) {
        const int m = bm + ty * 2 + i;
        const float bvv = bias[m];
#pragma unroll
        for (int j = 0; j < 8; j++) {
            const int n = tx * 8 + j;   // 0..127 (pad region zeroed)
            const float v = (n < N) ? (acc[i][j] + bvv) : 0.f;
            if (m < 512) kct[((size_t)b * 128 + n) * 512 + m] = f2bf(v * scl);
            else         vcn[((size_t)b * 512 + (m - 512)) * 128 + n] = f2bf(v);
        }
    }
}

// ================================================================
// MFMA flash attention (bf16 inputs, fp32 softmax/accum).
// Qt [b][1024][512] (pre-scaled), Kt [b][spad][512] (pre-scaled),
// Vn [b][512][spad]. Ob [b][1024][512] fp32 (CROSS accumulates).
// Block: 128 t-rows, 4 waves (32 t each), KVBLK=64. LDS 32KB:
//   [0..16K)  Q (128x64 bf16) -> per-wave 4KB becomes P (32x64 bf16)
//   [16K..24K) K tile, [24K..32K) V tile. All 128B rows, XOR swizzle
//   byte ^= ((row&7)<<4) (round-1-verified pattern).
template<bool CROSS>
__global__ __launch_bounds__(256) void mattn_k(
    const ushort_t* __restrict__ Qt, const ushort_t* __restrict__ Kt,
    const ushort_t* __restrict__ Vn, float* __restrict__ Ob,
    const int* __restrict__ mask, int spad, int slen,
    size_t k_bs, size_t v_bs, int v_rs)
{
    __shared__ __align__(16) char smem[32768];
    char* QP = smem;
    char* Ks = smem + 16384;
    char* Vs = smem + 24576;

    const int b = blockIdx.z, h = blockIdx.y, tb = blockIdx.x * 128;
    const int tid = threadIdx.x;
    const int l = tid & 63, wv = tid >> 6;
    const int lrow = l & 15, lk = l >> 4;
    const int lsw = (l & 7) << 4;

    // ---- stage Q (128 x 64) ----
#pragma unroll
    for (int p = 0; p < 4; p++) {
        const int q = tid + p * 256, row = q >> 3, ch = q & 7;
        s16x8 v = *(const s16x8*)(Qt + ((size_t)b * 1024 + tb + row) * 512 + h * 64 + ch * 8);
        *(s16x8*)(QP + row * 128 + ((ch * 16) ^ ((row & 7) << 4))) = v;
    }
    __syncthreads();
    // ---- Q frags to regs (wave reads only its own 32 rows == its P region) ----
    s16x8 qf[2][2];
#pragma unroll
    for (int mf = 0; mf < 2; mf++)
#pragma unroll
        for (int ks = 0; ks < 2; ks++) {
            const int row = wv * 32 + mf * 16 + lrow;
            qf[mf][ks] = *(const s16x8*)(QP + row * 128 + ((lk * 16 + ks * 64) ^ lsw));
        }

    f32x4 Oa[2][4];
    const f32x4 zf = {0.f, 0.f, 0.f, 0.f};
    float mo[2][4], lo[2][4];
#pragma unroll
    for (int mf = 0; mf < 2; mf++)
#pragma unroll
        for (int r = 0; r < 4; r++) { mo[mf][r] = -INFINITY; lo[mf][r] = 0.f; }
#pragma unroll
    for (int mf = 0; mf < 2; mf++)
#pragma unroll
        for (int nf = 0; nf < 4; nf++) Oa[mf][nf] = zf;

    char* Pw = QP + wv * 4096;
    const int nst = spad >> 6;
    for (int st = 0; st < nst; st++) {
        const int s0 = st * 64;
        // ---- stage K [s][c], V [c][s] (64x64 each) ----
#pragma unroll
        for (int p = 0; p < 2; p++) {
            const int q = tid + p * 256, row = q >> 3, ch = q & 7;
            const int loff = row * 128 + ((ch * 16) ^ ((row & 7) << 4));
            s16x8 kv = *(const s16x8*)(Kt + (size_t)b * k_bs + (size_t)(s0 + row) * 512 + h * 64 + ch * 8);
            *(s16x8*)(Ks + loff) = kv;
            s16x8 vv = *(const s16x8*)(Vn + (size_t)b * v_bs + (size_t)(h * 64 + row) * v_rs + s0 + ch * 8);
            *(s16x8*)(Vs + loff) = vv;
        }
        __syncthreads();
        // ---- QK^T: S[t][s], K-dim = 64 c ----
        f32x4 sf[2][4];
#pragma unroll
        for (int mf = 0; mf < 2; mf++)
#pragma unroll
            for (int nf = 0; nf < 4; nf++) sf[mf][nf] = zf;
#pragma unroll
        for (int ks = 0; ks < 2; ks++) {
            s16x8 bfr[4];
#pragma unroll
            for (int nf = 0; nf < 4; nf++) {
                const int row = nf * 16 + lrow;
                bfr[nf] = *(const s16x8*)(Ks + row * 128 + ((lk * 16 + ks * 64) ^ lsw));
            }
#pragma unroll
            for (int mf = 0; mf < 2; mf++)
#pragma unroll
                for (int nf = 0; nf < 4; nf++)
                    sf[mf][nf] = __builtin_amdgcn_mfma_f32_16x16x32_bf16(qf[mf][ks], bfr[nf], sf[mf][nf], 0, 0, 0);
        }
        // ---- mask (cross) ----
        bool vld[4];
        if (CROSS) {
#pragma unroll
            for (int nf = 0; nf < 4; nf++) {
                const int s = s0 + nf * 16 + lrow;
                vld[nf] = (s < slen) ? (mask[b * 77 + s] != 0) : false;
            }
        }
        // ---- online softmax per t-row; write P (bf16, swizzled) ----
        float alpha[2][4];
#pragma unroll
        for (int mf = 0; mf < 2; mf++) {
#pragma unroll
            for (int reg = 0; reg < 4; reg++) {
                float v0 = sf[mf][0][reg], v1 = sf[mf][1][reg];
                float v2 = sf[mf][2][reg], v3 = sf[mf][3][reg];
                if (CROSS) {
                    v0 = vld[0] ? v0 : -INFINITY;
                    v1 = vld[1] ? v1 : -INFINITY;
                    v2 = vld[2] ? v2 : -INFINITY;
                    v3 = vld[3] ? v3 : -INFINITY;
                }
                float rm = fmaxf(fmaxf(v0, v1), fmaxf(v2, v3));
#pragma unroll
                for (int m = 1; m < 16; m <<= 1) rm = fmaxf(rm, __shfl_xor(rm, m));
                const float mn = fmaxf(mo[mf][reg], rm);
                const float mnf = (mn == -INFINITY) ? 0.f : mn;
                const float al = __expf(mo[mf][reg] - mnf);
                const float p0 = __expf(v0 - mnf), p1 = __expf(v1 - mnf);
                const float p2 = __expf(v2 - mnf), p3 = __expf(v3 - mnf);
                float rs = p0 + p1 + p2 + p3;
#pragma unroll
                for (int m = 1; m < 16; m <<= 1) rs += __shfl_xor(rs, m);
                lo[mf][reg] = lo[mf][reg] * al + rs;
                mo[mf][reg] = mn;
                alpha[mf][reg] = al;
                const int prow = mf * 16 + lk * 4 + reg;
                const int rsw = (prow & 7) << 4;
                char* base = Pw + prow * 128;
                *(ushort_t*)(base + ((0 * 32 + lrow * 2) ^ rsw)) = f2bf(p0);
                *(ushort_t*)(base + ((1 * 32 + lrow * 2) ^ rsw)) = f2bf(p1);
                *(ushort_t*)(base + ((2 * 32 + lrow * 2) ^ rsw)) = f2bf(p2);
                *(ushort_t*)(base + ((3 * 32 + lrow * 2) ^ rsw)) = f2bf(p3);
            }
        }
        // ---- rescale O, then PV: O[t][c] += P[t][s] V[c][s], K-dim = 64 s ----
#pragma unroll
        for (int mf = 0; mf < 2; mf++)
#pragma unroll
            for (int nf = 0; nf < 4; nf++)
#pragma unroll
                for (int reg = 0; reg < 4; reg++) Oa[mf][nf][reg] *= alpha[mf][reg];
#pragma unroll
        for (int ks = 0; ks < 2; ks++) {
            s16x8 pa[2], vf[4];
#pragma unroll
            for (int mf = 0; mf < 2; mf++) {
                const int row = mf * 16 + lrow;
                pa[mf] = *(const s16x8*)(Pw + row * 128 + ((lk * 16 + ks * 64) ^ lsw));
            }
#pragma unroll
            for (int nf = 0; nf < 4; nf++) {
                const int row = nf * 16 + lrow;
                vf[nf] = *(const s16x8*)(Vs + row * 128 + ((lk * 16 + ks * 64) ^ lsw));
            }
#pragma unroll
            for (int mf = 0; mf < 2; mf++)
#pragma unroll
                for (int nf = 0; nf < 4; nf++)
                    Oa[mf][nf] = __builtin_amdgcn_mfma_f32_16x16x32_bf16(pa[mf], vf[nf], Oa[mf][nf], 0, 0, 0);
        }
        __syncthreads();
    }
    // ---- epilogue: /l, write [b][t][c] (16 contiguous c per 16 lanes) ----
    float rl[2][4];
#pragma unroll
    for (int mf = 0; mf < 2; mf++)
#pragma unroll
        for (int r = 0; r < 4; r++)
            rl[mf][r] = (lo[mf][r] > 0.f) ? 1.f / lo[mf][r] : 0.f;
#pragma unroll
    for (int mf = 0; mf < 2; mf++)
#pragma unroll
        for (int reg = 0; reg < 4; reg++) {
            const int t = tb + wv * 32 + mf * 16 + lk * 4 + reg;
            float* dr = Ob + ((size_t)b * 1024 + t) * 512 + h * 64 + lrow;
#pragma unroll
            for (int nf = 0; nf < 4; nf++) {
                const float v = Oa[mf][nf][reg] * rl[mf][reg];
                if (CROSS) dr[nf * 16] += v;
                else       dr[nf * 16] = v;
            }
        }
}

// ================================================================
extern "C" void kernel_launch(void* const* d_in, const int* in_sizes, int n_in,
                              void* d_out, int out_size, void* d_ws, size_t ws_size,
                              hipStream_t stream) {
    (void)in_sizes; (void)n_in; (void)out_size; (void)ws_size;
    const float* x        = (const float*)d_in[0];
    const float* cond     = (const float*)d_in[1];
    const int*   cmask    = (const int*)  d_in[2];
    const float* gn_w     = (const float*)d_in[3];
    const float* gn_b     = (const float*)d_in[4];
    const float* qkv_w    = (const float*)d_in[5];
    const float* qkv_b    = (const float*)d_in[6];
    const float* ln_w     = (const float*)d_in[7];
    const float* ln_b     = (const float*)d_in[8];
    const float* kvc_w    = (const float*)d_in[9];
    const float* kvc_b    = (const float*)d_in[10];
    const float* proj_w   = (const float*)d_in[11];
    const float* proj_b   = (const float*)d_in[12];
    const float* ffn_gn_w = (const float*)d_in[13];
    const float* ffn_gn_b = (const float*)d_in[14];
    const float* ffn_w1   = (const float*)d_in[15];
    const float* ffn_b1   = (const float*)d_in[16];
    const float* ffn_w2   = (const float*)d_in[17];
    const float* ffn_b2   = (const float*)d_in[18];

    // Workspace (float units), total 28,801,024 fl ~= 115.2 MiB.
    float* ws    = (float*)d_ws;
    float* gn1_s = ws;                  float* gn1_b = ws + 4096;
    float* gn2_s = ws + 8192;           float* gn2_b = ws + 12288;
    float* cnt   = ws + 16384;          // 473088: cn_t [8][768][77]
    float* x1    = ws + 489472;         // 4194304
    ushort_t* ts_h = (ushort_t*)(ws + 4683776);  // split activation slot
    ushort_t* ts_l = ts_h + 4194304;             // (pair = 4,194,304 fl)
    // overlay region at fl 8878080 (16,777,216 fl):
    //   phase A (qkv..proj): qt, kt, vn, hb, kct, vcn
    //   phase B (ffn):       yt pair
    ushort_t* qt  = (ushort_t*)(ws + 8878080);   // [8][1024][512] bf16
    ushort_t* kt  = qt + 4194304;                // [8][1024][512]
    ushort_t* vn  = kt + 4194304;                // [8][512][1024]
    float*    hb  = ws + 15169536;               // [8][1024][512] fp32
    ushort_t* kct = (ushort_t*)(ws + 19363840);  // [8][128][512]
    ushort_t* vcn = kct + 524288;                // [8][512][128]
    ushort_t* yt_h = (ushort_t*)(ws + 8878080);  // [8][1024][2048] x2
    ushort_t* yt_l = yt_h + 16777216;
    ushort_t* wq_h = (ushort_t*)(ws + 25655296);
    ushort_t* wq_l = wq_h + 786432;
    ushort_t* wp_h = wq_l + 786432;
    ushort_t* wp_l = wp_h + 262144;
    ushort_t* w1_h = wp_l + 262144;
    ushort_t* w1_l = w1_h + 1048576;
    ushort_t* w2_h = w1_l + 1048576;
    ushort_t* w2_l = w2_h + 1048576;

    // 1) GN1 stats; split weights
    gn_stats_k<<<256, 256, 0, stream>>>(x, gn_w, gn_b, gn1_s, gn1_b);
    wsplit_k<<<768, 256, 0, stream>>>(qkv_w, wq_h, wq_l, 196608);
    wsplit_k<<<256, 256, 0, stream>>>(proj_w, wp_h, wp_l, 65536);
    wsplit_k<<<1024, 256, 0, stream>>>(ffn_w1, w1_h, w1_l, 262144);
    wsplit_k<<<1024, 256, 0, stream>>>(ffn_w2, w2_h, w2_l, 262144);
    // 2) xt1 = T(GN1(x)) split
    tsplit_k<true><<<dim3(16, 8, 8), 256, 0, stream>>>(x, gn1_s, gn1_b, ts_h, ts_l, 512, 1024);
    // 3) qkv GEMM: q/k rows -> qt/kt (transposed bf16, *scale); v rows -> vn
    mgemm_k<3><<<dim3(8, 8, 8), 256, 0, stream>>>(
        wq_h, wq_l, ts_h, ts_l, qkv_b, nullptr, nullptr, qt, kt, 1024, 512, 1024);
    mgemm_k<4><<<dim3(8, 4, 8), 256, 0, stream>>>(
        wq_h + (size_t)1024 * 512, wq_l + (size_t)1024 * 512, ts_h, ts_l,
        qkv_b + 1024, nullptr, nullptr, vn, nullptr, 512, 512, 1024);
    // 4) self-attention (MFMA) -> hb [b][t][c]
    mattn_k<false><<<dim3(8, 8, 8), 256, 0, stream>>>(
        qt, kt, vn, hb, nullptr, 1024, 1024,
        (size_t)1024 * 512, (size_t)512 * 1024, 1024);
    // 5) LN(cond) transposed; kvc GEMM -> kct/vcn (bf16, padded)
    ln_t_k<<<616, 256, 0, stream>>>(cond, ln_w, ln_b, cnt);
    gemm_small_k<<<dim3(1, 32, 8), 256, 0, stream>>>(kvc_w, cnt, kvc_b, kct, vcn, 1024, 768, 77);
    // 6) cross-attention (MFMA, masked), accumulate into hb
    mattn_k<true><<<dim3(8, 8, 8), 256, 0, stream>>>(
        qt, kct, vcn, hb, cmask, 128, 77,
        (size_t)128 * 512, (size_t)512 * 128, 128);
    // 7) split hb (already [b][t][c] = [N][K]) -> ts; proj GEMM
    wsplit_k<<<1024, 256, 0, stream>>>(hb, ts_h, ts_l, 1048576);
    mgemm_k<1><<<dim3(8, 4, 8), 256, 0, stream>>>(
        wp_h, wp_l, ts_h, ts_l, proj_b, x, x1, nullptr, nullptr, 512, 512, 1024);
    // 8) GN2; x1t split; ffn1 (gelu, transposed bf16 out); ffn2 (+res)
    gn_stats_k<<<256, 256, 0, stream>>>(x1, ffn_gn_w, ffn_gn_b, gn2_s, gn2_b);
    tsplit_k<true><<<dim3(16, 8, 8), 256, 0, stream>>>(x1, gn2_s, gn2_b, ts_h, ts_l, 512, 1024);
    mgemm_k<2><<<dim3(8, 16, 8), 256, 0, stream>>>(
        w1_h, w1_l, ts_h, ts_l, ffn_b1, nullptr, nullptr, yt_h, yt_l, 2048, 512, 1024);
    mgemm_k<1><<<dim3(8, 4, 8), 256, 0, stream>>>(
        w2_h, w2_l, yt_h, yt_l, ffn_b2, x1, (float*)d_out, nullptr, nullptr, 512, 2048, 1024);
}

// Round 6
// 526.256 us; speedup vs baseline: 1.5991x; 1.0416x over previous
//
#include <hip/hip_runtime.h>
#include <math.h>

// B=8, C=512, L=1024, heads=8x64, GROUPS=32, cond Lc=77 D=768. fp32 in/out.
// GEMMs: bf16x3-split MFMA with global_load_lds staging (pre-swizzled src).
// Attention: bf16 MFMA flash, TBLK=64 (4 blocks/CU) for occupancy.

typedef float f32x4 __attribute__((ext_vector_type(4)));
typedef short s16x8 __attribute__((ext_vector_type(8)));
typedef unsigned short ushort_t;

typedef const void __attribute__((address_space(1)))* gas_ptr;
typedef void __attribute__((address_space(3)))* las_ptr;

__device__ __forceinline__ void gload16(const void* g, void* l) {
    // async global->LDS, 16B/lane; LDS dest = wave-uniform base + lane*16
    __builtin_amdgcn_global_load_lds((gas_ptr)g, (las_ptr)l, 16, 0, 0);
}

__device__ __forceinline__ float gelu_exact(float v) {
    return 0.5f * v * (1.0f + erff(v * 0.70710678118654752f));
}
__device__ __forceinline__ ushort_t f2bf(float f) {
    unsigned int u = __float_as_uint(f);
    return (ushort_t)((u + 0x7FFFu + ((u >> 16) & 1u)) >> 16);
}
__device__ __forceinline__ float bf2f(ushort_t h) {
    return __uint_as_float(((unsigned int)h) << 16);
}

// ================================================================
__global__ __launch_bounds__(256) void gn_stats_k(
    const float* __restrict__ x, const float* __restrict__ gw,
    const float* __restrict__ gb, float* __restrict__ oscl, float* __restrict__ obia)
{
    const int blk = blockIdx.x;
    const int b = blk >> 5, g = blk & 31;
    const float4* base = (const float4*)(x + ((size_t)b * 512 + (size_t)g * 16) * 1024);
    float s = 0.f, sq = 0.f;
    for (int i = threadIdx.x; i < 4096; i += 256) {
        float4 v = base[i];
        s  += v.x + v.y + v.z + v.w;
        sq += v.x * v.x + v.y * v.y + v.z * v.z + v.w * v.w;
    }
#pragma unroll
    for (int m = 32; m >= 1; m >>= 1) { s += __shfl_xor(s, m); sq += __shfl_xor(sq, m); }
    __shared__ float ls[4], lq[4];
    const int wid = threadIdx.x >> 6;
    if ((threadIdx.x & 63) == 0) { ls[wid] = s; lq[wid] = sq; }
    __syncthreads();
    if (threadIdx.x == 0) {
        float S = ls[0] + ls[1] + ls[2] + ls[3];
        float Q = lq[0] + lq[1] + lq[2] + lq[3];
        float mean = S * (1.f / 16384.f);
        float var  = Q * (1.f / 16384.f) - mean * mean;
        float istd = rsqrtf(var + 1e-5f);
#pragma unroll
        for (int cc = 0; cc < 16; cc++) {
            int c = g * 16 + cc;
            float sc = gw[c] * istd;
            oscl[b * 512 + c] = sc;
            obia[b * 512 + c] = gb[c] - mean * sc;
        }
    }
}

// ================================================================
__global__ __launch_bounds__(256) void ln_t_k(
    const float* __restrict__ cond, const float* __restrict__ lw,
    const float* __restrict__ lb, float* __restrict__ out)
{
    const int blk = blockIdx.x;
    const int b = blk / 77, t = blk % 77;
    const float* row = cond + ((size_t)b * 77 + t) * 768;
    float v[3];
    float s = 0.f, sq = 0.f;
#pragma unroll
    for (int p = 0; p < 3; p++) {
        v[p] = row[threadIdx.x + p * 256];
        s += v[p]; sq += v[p] * v[p];
    }
#pragma unroll
    for (int m = 32; m >= 1; m >>= 1) { s += __shfl_xor(s, m); sq += __shfl_xor(sq, m); }
    __shared__ float ls[4], lq[4], stat[2];
    const int wid = threadIdx.x >> 6;
    if ((threadIdx.x & 63) == 0) { ls[wid] = s; lq[wid] = sq; }
    __syncthreads();
    if (threadIdx.x == 0) {
        float S = ls[0] + ls[1] + ls[2] + ls[3];
        float Q = lq[0] + lq[1] + lq[2] + lq[3];
        float mean = S * (1.f / 768.f);
        float var  = Q * (1.f / 768.f) - mean * mean;
        stat[0] = mean; stat[1] = rsqrtf(var + 1e-5f);
    }
    __syncthreads();
    const float mean = stat[0], istd = stat[1];
#pragma unroll
    for (int p = 0; p < 3; p++) {
        int d = threadIdx.x + p * 256;
        out[((size_t)b * 768 + d) * 77 + t] = (v[p] - mean) * istd * lw[d] + lb[d];
    }
}

// ================================================================
// fp32 -> (hi, lo) bf16 split, elementwise (weights and hb).
__global__ __launch_bounds__(256) void wsplit_k(
    const float* __restrict__ w, ushort_t* __restrict__ oh, ushort_t* __restrict__ ol, int n4)
{
    for (int i = blockIdx.x * 256 + threadIdx.x; i < n4; i += gridDim.x * 256) {
        float4 v = ((const float4*)w)[i];
        ushort4 h, l;
        h.x = f2bf(v.x); l.x = f2bf(v.x - bf2f(h.x));
        h.y = f2bf(v.y); l.y = f2bf(v.y - bf2f(h.y));
        h.z = f2bf(v.z); l.z = f2bf(v.z - bf2f(h.z));
        h.w = f2bf(v.w); l.w = f2bf(v.w - bf2f(h.w));
        ((ushort4*)oh)[i] = h;
        ((ushort4*)ol)[i] = l;
    }
}

// ================================================================
// Transpose + split (+ optional fused GN scale/bias): [b][R][C] -> [b][C][R].
template<bool SB>
__global__ __launch_bounds__(256) void tsplit_k(
    const float* __restrict__ in, const float* __restrict__ scl,
    const float* __restrict__ bia, ushort_t* __restrict__ oh,
    ushort_t* __restrict__ ol, int R, int C)
{
    __shared__ ushort_t Lh[64][68], Ll[64][68];
    const int b = blockIdx.z, r0 = blockIdx.y * 64, c0 = blockIdx.x * 64;
    const int tid = threadIdx.x;
#pragma unroll
    for (int p = 0; p < 4; p++) {
        const int q = tid + p * 256;
        const int rr = q >> 4, cc4 = (q & 15) * 4;
        float4 v = *(const float4*)(in + ((size_t)b * R + r0 + rr) * C + c0 + cc4);
        if (SB) {
            const float s = scl[b * R + r0 + rr], o = bia[b * R + r0 + rr];
            v.x = v.x * s + o; v.y = v.y * s + o; v.z = v.z * s + o; v.w = v.w * s + o;
        }
        ushort4 h, l;
        h.x = f2bf(v.x); l.x = f2bf(v.x - bf2f(h.x));
        h.y = f2bf(v.y); l.y = f2bf(v.y - bf2f(h.y));
        h.z = f2bf(v.z); l.z = f2bf(v.z - bf2f(h.z));
        h.w = f2bf(v.w); l.w = f2bf(v.w - bf2f(h.w));
        *(ushort4*)&Lh[rr][cc4] = h;
        *(ushort4*)&Ll[rr][cc4] = l;
    }
    __syncthreads();
#pragma unroll
    for (int p = 0; p < 4; p++) {
        const int q = tid + p * 256;
        const int nn = q >> 4, rr4 = (q & 15) * 4;
        ushort4 h, l;
        h.x = Lh[rr4 + 0][nn]; h.y = Lh[rr4 + 1][nn];
        h.z = Lh[rr4 + 2][nn]; h.w = Lh[rr4 + 3][nn];
        l.x = Ll[rr4 + 0][nn]; l.y = Ll[rr4 + 1][nn];
        l.z = Ll[rr4 + 2][nn]; l.w = Ll[rr4 + 3][nn];
        *(ushort4*)(oh + ((size_t)b * C + c0 + nn) * R + r0 + rr4) = h;
        *(ushort4*)(ol + ((size_t)b * C + c0 + nn) * R + r0 + rr4) = l;
    }
}

// ================================================================
// MFMA GEMM (bf16x3). W (hi,lo) [M][K]; X (hi,lo) transposed [b][N][K].
// 128x128xBK64, 4 waves, 64x64/wave. Staging via global_load_lds (16B):
// LDS dest is linear (wave base + lane*16); the T2 swizzle is applied by
// pre-XORing the SOURCE chunk index (chunk' = (l&7)^(l>>3)) -> LDS content
// is byte-identical to the round-1-verified swizzled layout, fragment
// reads unchanged (m173 pattern).
// MODE 1: +bias+res fp32 out. MODE 2: +bias+gelu, transposed split bf16 out.
// MODE 3: +bias, *attn-scale, transposed bf16 -> qt/kt. MODE 4: +bias, bf16 [M][N].
template<int MODE>
__global__ __launch_bounds__(256, 2) void mgemm_k(
    const ushort_t* __restrict__ Wh, const ushort_t* __restrict__ Wl,
    const ushort_t* __restrict__ Xh, const ushort_t* __restrict__ Xl,
    const float* __restrict__ bias, const float* __restrict__ res,
    float* __restrict__ out, ushort_t* __restrict__ outh, ushort_t* __restrict__ outl,
    int M, int K, int N)
{
    __shared__ __align__(16) char smem[65536];
    char* As_h = smem;
    char* As_l = smem + 16384;
    char* Bs_h = smem + 32768;
    char* Bs_l = smem + 49152;

    const int b  = blockIdx.z;
    const int bm = blockIdx.y * 128, bn = blockIdx.x * 128;
    const int tid = threadIdx.x;
    const int l = tid & 63, wv4 = tid >> 6;
    const int lr8 = l >> 3;              // row within wave slice (0..7)
    const int lch = (l & 7) ^ lr8;       // pre-swizzled source chunk

    const size_t wrow = (size_t)(bm + wv4 * 8 + lr8);
    const size_t xrow = (size_t)(bn + wv4 * 8 + lr8);
    const ushort_t* WhB = Wh + wrow * K + lch * 8;
    const ushort_t* WlB = Wl + wrow * K + lch * 8;
    const ushort_t* XhB = Xh + ((size_t)b * N + xrow) * K + lch * 8;
    const ushort_t* XlB = Xl + ((size_t)b * N + xrow) * K + lch * 8;

    // fragment addressing (unchanged, reads with the XOR)
    const int wm   = (wv4 >> 1) * 64, wn = (wv4 & 1) * 64;
    const int lrow = l & 15, lk = l >> 4;
    const int fswz = (l & 7) << 4;
    const int akb0 = (lk * 16) ^ fswz;
    const int akb1 = (64 + lk * 16) ^ fswz;
    const int abase = (wm + lrow) * 128;
    const int bbase = (wn + lrow) * 128;

    f32x4 acc[4][4];
    const f32x4 zf = {0.f, 0.f, 0.f, 0.f};
#pragma unroll
    for (int i = 0; i < 4; i++)
#pragma unroll
        for (int j = 0; j < 4; j++) acc[i][j] = zf;

    for (int k0 = 0; k0 < K; k0 += 64) {
#pragma unroll
        for (int p = 0; p < 4; p++) {
            const size_t ro = (size_t)(p * 32) * K + k0;
            const int lo_ = (p * 32 + wv4 * 8) * 128;   // wave-uniform LDS base
            gload16(WhB + ro, As_h + lo_);
            gload16(WlB + ro, As_l + lo_);
            gload16(XhB + ro, Bs_h + lo_);
            gload16(XlB + ro, Bs_l + lo_);
        }
        __syncthreads();
#pragma unroll
        for (int kk = 0; kk < 2; kk++) {
            const int akb = kk ? akb1 : akb0;
            s16x8 ah[4], al[4];
#pragma unroll
            for (int mf = 0; mf < 4; mf++) {
                ah[mf] = *(const s16x8*)(As_h + abase + mf * 2048 + akb);
                al[mf] = *(const s16x8*)(As_l + abase + mf * 2048 + akb);
            }
#pragma unroll
            for (int nf = 0; nf < 4; nf++) {
                s16x8 bh = *(const s16x8*)(Bs_h + bbase + nf * 2048 + akb);
                s16x8 bl = *(const s16x8*)(Bs_l + bbase + nf * 2048 + akb);
#pragma unroll
                for (int mf = 0; mf < 4; mf++) {
                    acc[mf][nf] = __builtin_amdgcn_mfma_f32_16x16x32_bf16(ah[mf], bh, acc[mf][nf], 0, 0, 0);
                    acc[mf][nf] = __builtin_amdgcn_mfma_f32_16x16x32_bf16(ah[mf], bl, acc[mf][nf], 0, 0, 0);
                    acc[mf][nf] = __builtin_amdgcn_mfma_f32_16x16x32_bf16(al[mf], bh, acc[mf][nf], 0, 0, 0);
                }
            }
        }
        __syncthreads();
    }

    // epilogue. C/D: col = lane&15 (n), row = (lane>>4)*4 + reg (m)  [m89]
    const int mb = bm + wm, nb = bn + wn;
    float bs[4][4];
#pragma unroll
    for (int mf = 0; mf < 4; mf++)
#pragma unroll
        for (int r = 0; r < 4; r++) bs[mf][r] = bias[mb + mf * 16 + lk * 4 + r];

    if (MODE == 2) {
#pragma unroll
        for (int mf = 0; mf < 4; mf++) {
            const int m0 = mb + mf * 16 + lk * 4;
#pragma unroll
            for (int nf = 0; nf < 4; nf++) {
                const int n = nb + nf * 16 + lrow;
                ushort4 hv, lv;
#pragma unroll
                for (int r = 0; r < 4; r++) {
                    float v = acc[mf][nf][r] + bs[mf][r];
                    v = gelu_exact(v);
                    ushort_t h = f2bf(v);
                    ushort_t lo = f2bf(v - bf2f(h));
                    if (r == 0) { hv.x = h; lv.x = lo; }
                    else if (r == 1) { hv.y = h; lv.y = lo; }
                    else if (r == 2) { hv.z = h; lv.z = lo; }
                    else { hv.w = h; lv.w = lo; }
                }
                *(ushort4*)(outh + ((size_t)b * N + n) * M + m0) = hv;
                *(ushort4*)(outl + ((size_t)b * N + n) * M + m0) = lv;
            }
        }
    } else if (MODE == 3) {
        const float scl = 0.35355339059327373f;
        ushort_t* dstb = (bm < 512) ? outh : outl;
        const int mloc = (bm < 512) ? mb : mb - 512;
#pragma unroll
        for (int mf = 0; mf < 4; mf++) {
            const int m0 = mloc + mf * 16 + lk * 4;
#pragma unroll
            for (int nf = 0; nf < 4; nf++) {
                const int n = nb + nf * 16 + lrow;
                ushort4 hv;
#pragma unroll
                for (int r = 0; r < 4; r++) {
                    float v = (acc[mf][nf][r] + bs[mf][r]) * scl;
                    if (r == 0) hv.x = f2bf(v);
                    else if (r == 1) hv.y = f2bf(v);
                    else if (r == 2) hv.z = f2bf(v);
                    else hv.w = f2bf(v);
                }
                *(ushort4*)(dstb + ((size_t)b * 1024 + n) * 512 + m0) = hv;
            }
        }
    } else if (MODE == 4) {
#pragma unroll
        for (int mf = 0; mf < 4; mf++)
#pragma unroll
            for (int r = 0; r < 4; r++) {
                const int m = mb + mf * 16 + lk * 4 + r;
#pragma unroll
                for (int nf = 0; nf < 4; nf++) {
                    const int n = nb + nf * 16 + lrow;
                    outh[((size_t)b * 512 + m) * 1024 + n] = f2bf(acc[mf][nf][r] + bs[mf][r]);
                }
            }
    } else {
        const size_t obase = (size_t)b * (size_t)M * N;
#pragma unroll
        for (int mf = 0; mf < 4; mf++)
#pragma unroll
            for (int r = 0; r < 4; r++) {
                const int m = mb + mf * 16 + lk * 4 + r;
                const size_t rowo = obase + (size_t)m * N;
#pragma unroll
                for (int nf = 0; nf < 4; nf++) {
                    const int n = nb + nf * 16 + lrow;
                    float v = acc[mf][nf][r] + bs[mf][r];
                    if (MODE == 1) v += res[rowo + n];
                    out[rowo + n] = v;
                }
            }
    }
}

// ================================================================
// kvc GEMM (M=1024, K=768, N=77 padded to 128). fp32 compute; epilogue emits
// kct bf16 [b][128][512] (transposed, *scale, zero-pad) and vcn bf16
// [b][512][128] (zero-pad).
__global__ __launch_bounds__(256, 2) void gemm_small_k(
    const float* __restrict__ W, const float* __restrict__ X,
    const float* __restrict__ bias, ushort_t* __restrict__ kct,
    ushort_t* __restrict__ vcn, int M, int K, int N)
{
    __shared__ float Ws[16][32];
    __shared__ float Xs[16][128];
    const int b  = blockIdx.z;
    const int bm = blockIdx.y * 32;
    const float* Wp = W + (size_t)bm * K;
    const float* Xp = X + (size_t)b * K * N;
    const int tid = threadIdx.x, tx = tid & 15, ty = tid >> 4;
    const int xr = tid >> 5, xc = (tid & 31) * 4;
    float acc[2][8];
#pragma unroll
    for (int i = 0; i < 2; i++)
#pragma unroll
        for (int j = 0; j < 8; j++) acc[i][j] = 0.f;

    for (int k0 = 0; k0 < K; k0 += 16) {
        {
            const int idx = tid * 2;
            const int r = idx >> 4, kk = idx & 15;
            float2 w2 = *(const float2*)(Wp + (size_t)r * K + k0 + kk);
            Ws[kk][r] = w2.x; Ws[kk + 1][r] = w2.y;
        }
#pragma unroll
        for (int p = 0; p < 2; p++) {
            const int kr = xr + p * 8;
            const float* xrow = Xp + (size_t)(k0 + kr) * N;
            float4 v;
            v.x = (xc + 0 < N) ? xrow[xc + 0] : 0.f;
            v.y = (xc + 1 < N) ? xrow[xc + 1] : 0.f;
            v.z = (xc + 2 < N) ? xrow[xc + 2] : 0.f;
            v.w = (xc + 3 < N) ? xrow[xc + 3] : 0.f;
            *(float4*)&Xs[kr][xc] = v;
        }
        __syncthreads();
#pragma unroll
        for (int kk = 0; kk < 16; kk++) {
            const float a0 = Ws[kk][ty * 2], a1 = Ws[kk][ty * 2 + 1];
            float bb[8];
            *(float4*)&bb[0] = *(const float4*)&Xs[kk][tx * 8];
            *(float4*)&bb[4] = *(const float4*)&Xs[kk][tx * 8 + 4];
#pragma unroll
            for (int j = 0; j < 8; j++) {
                acc[0][j] = fmaf(a0, bb[j], acc[0][j]);
                acc[1][j] = fmaf(a1, bb[j], acc[1][j]);
            }
        }
        __syncthreads();
    }
    const float scl = 0.35355339059327373f;
#pragma unroll
    for (int i = 0; i < 2; i++) {
        const int m = bm + ty * 2 + i;
        const float bvv = bias[m];
#pragma unroll
        for (int j = 0; j < 8; j++) {
            const int n = tx * 8 + j;   // 0..127 (pad region zeroed)
            const float v = (n < N) ? (acc[i][j] + bvv) : 0.f;
            if (m < 512) kct[((size_t)b * 128 + n) * 512 + m] = f2bf(v * scl);
            else         vcn[((size_t)b * 512 + (m - 512)) * 128 + n] = f2bf(v);
        }
    }
}

// ================================================================
// MFMA flash attention (bf16 inputs, fp32 softmax/accum).
// Qt [b][1024][512] (pre-scaled), Kt [b][spad][512] (pre-scaled),
// Vn [b][512][spad]. Ob [b][1024][512] fp32 (CROSS accumulates).
// TBLK=64 t-rows/block, 4 waves x 16 rows -> grid 1024 blocks (4/CU),
// 16 waves/CU (round-5 counters: 512 blocks gave Occupancy 10.5%,
// MfmaUtil 7% -> latency-bound; this doubles resident waves).
// LDS 24KB: QP 8K (Q 64x64 -> per-wave P 16x64), Ks 8K, Vs 8K.
// Staging via global_load_lds + pre-swizzled source (content identical
// to the verified byte^=((row&7)<<4) layout).
template<bool CROSS>
__global__ __launch_bounds__(256) void mattn_k(
    const ushort_t* __restrict__ Qt, const ushort_t* __restrict__ Kt,
    const ushort_t* __restrict__ Vn, float* __restrict__ Ob,
    const int* __restrict__ mask, int spad, int slen,
    size_t k_bs, size_t v_bs, int v_rs)
{
    __shared__ __align__(16) char smem[24576];
    char* QP = smem;
    char* Ks = smem + 8192;
    char* Vs = smem + 16384;

    const int b = blockIdx.z, h = blockIdx.y, tb = blockIdx.x * 64;
    const int tid = threadIdx.x;
    const int l = tid & 63, wv = tid >> 6;
    const int lrow = l & 15, lk = l >> 4;
    const int lsw = (l & 7) << 4;
    const int lr8 = l >> 3, lch = (l & 7) ^ lr8;

    // ---- stage Q (64 x 64) ----
#pragma unroll
    for (int p = 0; p < 2; p++) {
        const int rb = p * 32 + wv * 8;
        gload16(Qt + ((size_t)b * 1024 + tb + rb + lr8) * 512 + h * 64 + lch * 8,
                QP + rb * 128);
    }
    __syncthreads();
    // ---- Q frags to regs (wave reads only its own 16 rows == its P region) ----
    s16x8 qf[2];
#pragma unroll
    for (int ks = 0; ks < 2; ks++) {
        const int row = wv * 16 + lrow;
        qf[ks] = *(const s16x8*)(QP + row * 128 + ((lk * 16 + ks * 64) ^ lsw));
    }

    f32x4 Oa[4];
    const f32x4 zf = {0.f, 0.f, 0.f, 0.f};
    float mo[4], lo[4];
#pragma unroll
    for (int r = 0; r < 4; r++) { mo[r] = -INFINITY; lo[r] = 0.f; Oa[r] = zf; }

    char* Pw = QP + wv * 2048;
    const int nst = spad >> 6;
    for (int st = 0; st < nst; st++) {
        const int s0 = st * 64;
        // ---- stage K [s][c], V [c][s] (64x64 each) ----
#pragma unroll
        for (int p = 0; p < 2; p++) {
            const int rb = p * 32 + wv * 8;
            gload16(Kt + (size_t)b * k_bs + (size_t)(s0 + rb + lr8) * 512 + h * 64 + lch * 8,
                    Ks + rb * 128);
            gload16(Vn + (size_t)b * v_bs + (size_t)(h * 64 + rb + lr8) * v_rs + s0 + lch * 8,
                    Vs + rb * 128);
        }
        __syncthreads();
        // ---- QK^T: S[t][s] ----
        f32x4 sf[4];
#pragma unroll
        for (int nf = 0; nf < 4; nf++) sf[nf] = zf;
#pragma unroll
        for (int ks = 0; ks < 2; ks++) {
            s16x8 bfr[4];
#pragma unroll
            for (int nf = 0; nf < 4; nf++) {
                const int row = nf * 16 + lrow;
                bfr[nf] = *(const s16x8*)(Ks + row * 128 + ((lk * 16 + ks * 64) ^ lsw));
            }
#pragma unroll
            for (int nf = 0; nf < 4; nf++)
                sf[nf] = __builtin_amdgcn_mfma_f32_16x16x32_bf16(qf[ks], bfr[nf], sf[nf], 0, 0, 0);
        }
        // ---- mask (cross) ----
        bool vld[4];
        if (CROSS) {
#pragma unroll
            for (int nf = 0; nf < 4; nf++) {
                const int s = s0 + nf * 16 + lrow;
                vld[nf] = (s < slen) ? (mask[b * 77 + s] != 0) : false;
            }
        }
        // ---- online softmax per t-row; write P (bf16, swizzled) ----
        float alpha[4];
#pragma unroll
        for (int reg = 0; reg < 4; reg++) {
            float v0 = sf[0][reg], v1 = sf[1][reg];
            float v2 = sf[2][reg], v3 = sf[3][reg];
            if (CROSS) {
                v0 = vld[0] ? v0 : -INFINITY;
                v1 = vld[1] ? v1 : -INFINITY;
                v2 = vld[2] ? v2 : -INFINITY;
                v3 = vld[3] ? v3 : -INFINITY;
            }
            float rm = fmaxf(fmaxf(v0, v1), fmaxf(v2, v3));
#pragma unroll
            for (int m = 1; m < 16; m <<= 1) rm = fmaxf(rm, __shfl_xor(rm, m));
            const float mn = fmaxf(mo[reg], rm);
            const float mnf = (mn == -INFINITY) ? 0.f : mn;
            const float al = __expf(mo[reg] - mnf);
            const float p0 = __expf(v0 - mnf), p1 = __expf(v1 - mnf);
            const float p2 = __expf(v2 - mnf), p3 = __expf(v3 - mnf);
            float rs = p0 + p1 + p2 + p3;
#pragma unroll
            for (int m = 1; m < 16; m <<= 1) rs += __shfl_xor(rs, m);
            lo[reg] = lo[reg] * al + rs;
            mo[reg] = mn;
            alpha[reg] = al;
            const int prow = lk * 4 + reg;
            const int rsw = (prow & 7) << 4;
            char* base = Pw + prow * 128;
            *(ushort_t*)(base + ((0 * 32 + lrow * 2) ^ rsw)) = f2bf(p0);
            *(ushort_t*)(base + ((1 * 32 + lrow * 2) ^ rsw)) = f2bf(p1);
            *(ushort_t*)(base + ((2 * 32 + lrow * 2) ^ rsw)) = f2bf(p2);
            *(ushort_t*)(base + ((3 * 32 + lrow * 2) ^ rsw)) = f2bf(p3);
        }
        // ---- rescale O, then PV ----
#pragma unroll
        for (int nf = 0; nf < 4; nf++)
#pragma unroll
            for (int reg = 0; reg < 4; reg++) Oa[nf][reg] *= alpha[reg];
#pragma unroll
        for (int ks = 0; ks < 2; ks++) {
            s16x8 pa = *(const s16x8*)(Pw + lrow * 128 + ((lk * 16 + ks * 64) ^ lsw));
            s16x8 vf[4];
#pragma unroll
            for (int nf = 0; nf < 4; nf++) {
                const int row = nf * 16 + lrow;
                vf[nf] = *(const s16x8*)(Vs + row * 128 + ((lk * 16 + ks * 64) ^ lsw));
            }
#pragma unroll
            for (int nf = 0; nf < 4; nf++)
                Oa[nf] = __builtin_amdgcn_mfma_f32_16x16x32_bf16(pa, vf[nf], Oa[nf], 0, 0, 0);
        }
        __syncthreads();
    }
    // ---- epilogue: /l, write [b][t][c] ----
    float rl[4];
#pragma unroll
    for (int r = 0; r < 4; r++) rl[r] = (lo[r] > 0.f) ? 1.f / lo[r] : 0.f;
#pragma unroll
    for (int reg = 0; reg < 4; reg++) {
        const int t = tb + wv * 16 + lk * 4 + reg;
        float* dr = Ob + ((size_t)b * 1024 + t) * 512 + h * 64 + lrow;
#pragma unroll
        for (int nf = 0; nf < 4; nf++) {
            const float v = Oa[nf][reg] * rl[reg];
            if (CROSS) dr[nf * 16] += v;
            else       dr[nf * 16] = v;
        }
    }
}

// ================================================================
extern "C" void kernel_launch(void* const* d_in, const int* in_sizes, int n_in,
                              void* d_out, int out_size, void* d_ws, size_t ws_size,
                              hipStream_t stream) {
    (void)in_sizes; (void)n_in; (void)out_size; (void)ws_size;
    const float* x        = (const float*)d_in[0];
    const float* cond     = (const float*)d_in[1];
    const int*   cmask    = (const int*)  d_in[2];
    const float* gn_w     = (const float*)d_in[3];
    const float* gn_b     = (const float*)d_in[4];
    const float* qkv_w    = (const float*)d_in[5];
    const float* qkv_b    = (const float*)d_in[6];
    const float* ln_w     = (const float*)d_in[7];
    const float* ln_b     = (const float*)d_in[8];
    const float* kvc_w    = (const float*)d_in[9];
    const float* kvc_b    = (const float*)d_in[10];
    const float* proj_w   = (const float*)d_in[11];
    const float* proj_b   = (const float*)d_in[12];
    const float* ffn_gn_w = (const float*)d_in[13];
    const float* ffn_gn_b = (const float*)d_in[14];
    const float* ffn_w1   = (const float*)d_in[15];
    const float* ffn_b1   = (const float*)d_in[16];
    const float* ffn_w2   = (const float*)d_in[17];
    const float* ffn_b2   = (const float*)d_in[18];

    // Workspace (float units), total 28,801,024 fl ~= 115.2 MiB.
    float* ws    = (float*)d_ws;
    float* gn1_s = ws;                  float* gn1_b = ws + 4096;
    float* gn2_s = ws + 8192;           float* gn2_b = ws + 12288;
    float* cnt   = ws + 16384;          // 473088: cn_t [8][768][77]
    float* x1    = ws + 489472;         // 4194304
    ushort_t* ts_h = (ushort_t*)(ws + 4683776);  // split activation slot
    ushort_t* ts_l = ts_h + 4194304;
    ushort_t* qt  = (ushort_t*)(ws + 8878080);   // [8][1024][512] bf16
    ushort_t* kt  = qt + 4194304;                // [8][1024][512]
    ushort_t* vn  = kt + 4194304;                // [8][512][1024]
    float*    hb  = ws + 15169536;               // [8][1024][512] fp32
    ushort_t* kct = (ushort_t*)(ws + 19363840);  // [8][128][512]
    ushort_t* vcn = kct + 524288;                // [8][512][128]
    ushort_t* yt_h = (ushort_t*)(ws + 8878080);  // [8][1024][2048] x2 (overlay)
    ushort_t* yt_l = yt_h + 16777216;
    ushort_t* wq_h = (ushort_t*)(ws + 25655296);
    ushort_t* wq_l = wq_h + 786432;
    ushort_t* wp_h = wq_l + 786432;
    ushort_t* wp_l = wp_h + 262144;
    ushort_t* w1_h = wp_l + 262144;
    ushort_t* w1_l = w1_h + 1048576;
    ushort_t* w2_h = w1_l + 1048576;
    ushort_t* w2_l = w2_h + 1048576;

    // 1) GN1 stats; split weights
    gn_stats_k<<<256, 256, 0, stream>>>(x, gn_w, gn_b, gn1_s, gn1_b);
    wsplit_k<<<768, 256, 0, stream>>>(qkv_w, wq_h, wq_l, 196608);
    wsplit_k<<<256, 256, 0, stream>>>(proj_w, wp_h, wp_l, 65536);
    wsplit_k<<<1024, 256, 0, stream>>>(ffn_w1, w1_h, w1_l, 262144);
    wsplit_k<<<1024, 256, 0, stream>>>(ffn_w2, w2_h, w2_l, 262144);
    // 2) xt1 = T(GN1(x)) split
    tsplit_k<true><<<dim3(16, 8, 8), 256, 0, stream>>>(x, gn1_s, gn1_b, ts_h, ts_l, 512, 1024);
    // 3) qkv GEMM: q/k rows -> qt/kt (transposed bf16, *scale); v rows -> vn
    mgemm_k<3><<<dim3(8, 8, 8), 256, 0, stream>>>(
        wq_h, wq_l, ts_h, ts_l, qkv_b, nullptr, nullptr, qt, kt, 1024, 512, 1024);
    mgemm_k<4><<<dim3(8, 4, 8), 256, 0, stream>>>(
        wq_h + (size_t)1024 * 512, wq_l + (size_t)1024 * 512, ts_h, ts_l,
        qkv_b + 1024, nullptr, nullptr, vn, nullptr, 512, 512, 1024);
    // 4) self-attention (MFMA) -> hb [b][t][c]
    mattn_k<false><<<dim3(16, 8, 8), 256, 0, stream>>>(
        qt, kt, vn, hb, nullptr, 1024, 1024,
        (size_t)1024 * 512, (size_t)512 * 1024, 1024);
    // 5) LN(cond) transposed; kvc GEMM -> kct/vcn (bf16, padded)
    ln_t_k<<<616, 256, 0, stream>>>(cond, ln_w, ln_b, cnt);
    gemm_small_k<<<dim3(1, 32, 8), 256, 0, stream>>>(kvc_w, cnt, kvc_b, kct, vcn, 1024, 768, 77);
    // 6) cross-attention (MFMA, masked), accumulate into hb
    mattn_k<true><<<dim3(16, 8, 8), 256, 0, stream>>>(
        qt, kct, vcn, hb, cmask, 128, 77,
        (size_t)128 * 512, (size_t)512 * 128, 128);
    // 7) split hb (already [b][t][c] = [N][K]) -> ts; proj GEMM
    wsplit_k<<<1024, 256, 0, stream>>>(hb, ts_h, ts_l, 1048576);
    mgemm_k<1><<<dim3(8, 4, 8), 256, 0, stream>>>(
        wp_h, wp_l, ts_h, ts_l, proj_b, x, x1, nullptr, nullptr, 512, 512, 1024);
    // 8) GN2; x1t split; ffn1 (gelu, transposed bf16 out); ffn2 (+res)
    gn_stats_k<<<256, 256, 0, stream>>>(x1, ffn_gn_w, ffn_gn_b, gn2_s, gn2_b);
    tsplit_k<true><<<dim3(16, 8, 8), 256, 0, stream>>>(x1, gn2_s, gn2_b, ts_h, ts_l, 512, 1024);
    mgemm_k<2><<<dim3(8, 16, 8), 256, 0, stream>>>(
        w1_h, w1_l, ts_h, ts_l, ffn_b1, nullptr, nullptr, yt_h, yt_l, 2048, 512, 1024);
    mgemm_k<1><<<dim3(8, 4, 8), 256, 0, stream>>>(
        w2_h, w2_l, yt_h, yt_l, ffn_b2, x1, (float*)d_out, nullptr, nullptr, 512, 2048, 1024);
}

// Round 7
// 437.402 us; speedup vs baseline: 1.9240x; 1.2031x over previous
//
#include <hip/hip_runtime.h>
#include <math.h>

// B=8, C=512, L=1024, heads=8x64, GROUPS=32, cond Lc=77 D=768. fp32 in/out.
// GEMMs: bf16x3-split MFMA with global_load_lds staging (pre-swizzled src).
// Attention: bf16 MFMA flash, TBLK=64. kvc: plain-bf16 MFMA (this round).

typedef float f32x4 __attribute__((ext_vector_type(4)));
typedef short s16x8 __attribute__((ext_vector_type(8)));
typedef unsigned short ushort_t;

typedef const void __attribute__((address_space(1)))* gas_ptr;
typedef void __attribute__((address_space(3)))* las_ptr;

__device__ __forceinline__ void gload16(const void* g, void* l) {
    // async global->LDS, 16B/lane; LDS dest = wave-uniform base + lane*16
    __builtin_amdgcn_global_load_lds((gas_ptr)g, (las_ptr)l, 16, 0, 0);
}

__device__ __forceinline__ float gelu_exact(float v) {
    return 0.5f * v * (1.0f + erff(v * 0.70710678118654752f));
}
__device__ __forceinline__ ushort_t f2bf(float f) {
    unsigned int u = __float_as_uint(f);
    return (ushort_t)((u + 0x7FFFu + ((u >> 16) & 1u)) >> 16);
}
__device__ __forceinline__ float bf2f(ushort_t h) {
    return __uint_as_float(((unsigned int)h) << 16);
}

// ================================================================
__global__ __launch_bounds__(256) void gn_stats_k(
    const float* __restrict__ x, const float* __restrict__ gw,
    const float* __restrict__ gb, float* __restrict__ oscl, float* __restrict__ obia)
{
    const int blk = blockIdx.x;
    const int b = blk >> 5, g = blk & 31;
    const float4* base = (const float4*)(x + ((size_t)b * 512 + (size_t)g * 16) * 1024);
    float s = 0.f, sq = 0.f;
    for (int i = threadIdx.x; i < 4096; i += 256) {
        float4 v = base[i];
        s  += v.x + v.y + v.z + v.w;
        sq += v.x * v.x + v.y * v.y + v.z * v.z + v.w * v.w;
    }
#pragma unroll
    for (int m = 32; m >= 1; m >>= 1) { s += __shfl_xor(s, m); sq += __shfl_xor(sq, m); }
    __shared__ float ls[4], lq[4];
    const int wid = threadIdx.x >> 6;
    if ((threadIdx.x & 63) == 0) { ls[wid] = s; lq[wid] = sq; }
    __syncthreads();
    if (threadIdx.x == 0) {
        float S = ls[0] + ls[1] + ls[2] + ls[3];
        float Q = lq[0] + lq[1] + lq[2] + lq[3];
        float mean = S * (1.f / 16384.f);
        float var  = Q * (1.f / 16384.f) - mean * mean;
        float istd = rsqrtf(var + 1e-5f);
#pragma unroll
        for (int cc = 0; cc < 16; cc++) {
            int c = g * 16 + cc;
            float sc = gw[c] * istd;
            oscl[b * 512 + c] = sc;
            obia[b * 512 + c] = gb[c] - mean * sc;
        }
    }
}

// ================================================================
// LayerNorm over D=768 -> bf16 cn [b][128][768] (t-rows 77..127 zeroed).
// Natural [N][K] operand for the kvc MFMA GEMM (no transpose pass).
__global__ __launch_bounds__(256) void ln_bf_k(
    const float* __restrict__ cond, const float* __restrict__ lw,
    const float* __restrict__ lb, ushort_t* __restrict__ out)
{
    const int blk = blockIdx.x;
    const int b = blk >> 7, t = blk & 127;
    ushort_t* orow = out + ((size_t)b * 128 + t) * 768;
    if (t >= 77) {
#pragma unroll
        for (int p = 0; p < 3; p++) orow[threadIdx.x + p * 256] = 0;
        return;
    }
    const float* row = cond + ((size_t)b * 77 + t) * 768;
    float v[3];
    float s = 0.f, sq = 0.f;
#pragma unroll
    for (int p = 0; p < 3; p++) {
        v[p] = row[threadIdx.x + p * 256];
        s += v[p]; sq += v[p] * v[p];
    }
#pragma unroll
    for (int m = 32; m >= 1; m >>= 1) { s += __shfl_xor(s, m); sq += __shfl_xor(sq, m); }
    __shared__ float ls[4], lq[4], stat[2];
    const int wid = threadIdx.x >> 6;
    if ((threadIdx.x & 63) == 0) { ls[wid] = s; lq[wid] = sq; }
    __syncthreads();
    if (threadIdx.x == 0) {
        float S = ls[0] + ls[1] + ls[2] + ls[3];
        float Q = lq[0] + lq[1] + lq[2] + lq[3];
        float mean = S * (1.f / 768.f);
        float var  = Q * (1.f / 768.f) - mean * mean;
        stat[0] = mean; stat[1] = rsqrtf(var + 1e-5f);
    }
    __syncthreads();
    const float mean = stat[0], istd = stat[1];
#pragma unroll
    for (int p = 0; p < 3; p++) {
        int d = threadIdx.x + p * 256;
        orow[d] = f2bf((v[p] - mean) * istd * lw[d] + lb[d]);
    }
}

// ================================================================
// fp32 -> (hi, lo) bf16 split, elementwise (weights and hb).
__global__ __launch_bounds__(256) void wsplit_k(
    const float* __restrict__ w, ushort_t* __restrict__ oh, ushort_t* __restrict__ ol, int n4)
{
    for (int i = blockIdx.x * 256 + threadIdx.x; i < n4; i += gridDim.x * 256) {
        float4 v = ((const float4*)w)[i];
        ushort4 h, l;
        h.x = f2bf(v.x); l.x = f2bf(v.x - bf2f(h.x));
        h.y = f2bf(v.y); l.y = f2bf(v.y - bf2f(h.y));
        h.z = f2bf(v.z); l.z = f2bf(v.z - bf2f(h.z));
        h.w = f2bf(v.w); l.w = f2bf(v.w - bf2f(h.w));
        ((ushort4*)oh)[i] = h;
        ((ushort4*)ol)[i] = l;
    }
}

// ================================================================
// fp32 -> bf16 cast (hi only), elementwise (kvc weight).
__global__ __launch_bounds__(256) void wcast_k(
    const float* __restrict__ w, ushort_t* __restrict__ oh, int n4)
{
    for (int i = blockIdx.x * 256 + threadIdx.x; i < n4; i += gridDim.x * 256) {
        float4 v = ((const float4*)w)[i];
        ushort4 h;
        h.x = f2bf(v.x); h.y = f2bf(v.y); h.z = f2bf(v.z); h.w = f2bf(v.w);
        ((ushort4*)oh)[i] = h;
    }
}

// ================================================================
// Transpose + split (+ optional fused GN scale/bias): [b][R][C] -> [b][C][R].
template<bool SB>
__global__ __launch_bounds__(256) void tsplit_k(
    const float* __restrict__ in, const float* __restrict__ scl,
    const float* __restrict__ bia, ushort_t* __restrict__ oh,
    ushort_t* __restrict__ ol, int R, int C)
{
    __shared__ ushort_t Lh[64][68], Ll[64][68];
    const int b = blockIdx.z, r0 = blockIdx.y * 64, c0 = blockIdx.x * 64;
    const int tid = threadIdx.x;
#pragma unroll
    for (int p = 0; p < 4; p++) {
        const int q = tid + p * 256;
        const int rr = q >> 4, cc4 = (q & 15) * 4;
        float4 v = *(const float4*)(in + ((size_t)b * R + r0 + rr) * C + c0 + cc4);
        if (SB) {
            const float s = scl[b * R + r0 + rr], o = bia[b * R + r0 + rr];
            v.x = v.x * s + o; v.y = v.y * s + o; v.z = v.z * s + o; v.w = v.w * s + o;
        }
        ushort4 h, l;
        h.x = f2bf(v.x); l.x = f2bf(v.x - bf2f(h.x));
        h.y = f2bf(v.y); l.y = f2bf(v.y - bf2f(h.y));
        h.z = f2bf(v.z); l.z = f2bf(v.z - bf2f(h.z));
        h.w = f2bf(v.w); l.w = f2bf(v.w - bf2f(h.w));
        *(ushort4*)&Lh[rr][cc4] = h;
        *(ushort4*)&Ll[rr][cc4] = l;
    }
    __syncthreads();
#pragma unroll
    for (int p = 0; p < 4; p++) {
        const int q = tid + p * 256;
        const int nn = q >> 4, rr4 = (q & 15) * 4;
        ushort4 h, l;
        h.x = Lh[rr4 + 0][nn]; h.y = Lh[rr4 + 1][nn];
        h.z = Lh[rr4 + 2][nn]; h.w = Lh[rr4 + 3][nn];
        l.x = Ll[rr4 + 0][nn]; l.y = Ll[rr4 + 1][nn];
        l.z = Ll[rr4 + 2][nn]; l.w = Ll[rr4 + 3][nn];
        *(ushort4*)(oh + ((size_t)b * C + c0 + nn) * R + r0 + rr4) = h;
        *(ushort4*)(ol + ((size_t)b * C + c0 + nn) * R + r0 + rr4) = l;
    }
}

// ================================================================
// MFMA GEMM (bf16x3). W (hi,lo) [M][K]; X (hi,lo) transposed [b][N][K].
// 128x128xBK64, 4 waves, 64x64/wave. Staging via global_load_lds (16B),
// T2 swizzle applied by pre-XORing the SOURCE chunk (m173 pattern).
// MODE 1: +bias+res fp32 out. MODE 2: +bias+gelu, transposed split bf16 out.
// MODE 3: +bias, *attn-scale, transposed bf16 -> qt/kt. MODE 4: +bias, bf16 [M][N].
template<int MODE>
__global__ __launch_bounds__(256, 2) void mgemm_k(
    const ushort_t* __restrict__ Wh, const ushort_t* __restrict__ Wl,
    const ushort_t* __restrict__ Xh, const ushort_t* __restrict__ Xl,
    const float* __restrict__ bias, const float* __restrict__ res,
    float* __restrict__ out, ushort_t* __restrict__ outh, ushort_t* __restrict__ outl,
    int M, int K, int N)
{
    __shared__ __align__(16) char smem[65536];
    char* As_h = smem;
    char* As_l = smem + 16384;
    char* Bs_h = smem + 32768;
    char* Bs_l = smem + 49152;

    const int b  = blockIdx.z;
    const int bm = blockIdx.y * 128, bn = blockIdx.x * 128;
    const int tid = threadIdx.x;
    const int l = tid & 63, wv4 = tid >> 6;
    const int lr8 = l >> 3;
    const int lch = (l & 7) ^ lr8;       // pre-swizzled source chunk

    const size_t wrow = (size_t)(bm + wv4 * 8 + lr8);
    const size_t xrow = (size_t)(bn + wv4 * 8 + lr8);
    const ushort_t* WhB = Wh + wrow * K + lch * 8;
    const ushort_t* WlB = Wl + wrow * K + lch * 8;
    const ushort_t* XhB = Xh + ((size_t)b * N + xrow) * K + lch * 8;
    const ushort_t* XlB = Xl + ((size_t)b * N + xrow) * K + lch * 8;

    const int wm   = (wv4 >> 1) * 64, wn = (wv4 & 1) * 64;
    const int lrow = l & 15, lk = l >> 4;
    const int fswz = (l & 7) << 4;
    const int akb0 = (lk * 16) ^ fswz;
    const int akb1 = (64 + lk * 16) ^ fswz;
    const int abase = (wm + lrow) * 128;
    const int bbase = (wn + lrow) * 128;

    f32x4 acc[4][4];
    const f32x4 zf = {0.f, 0.f, 0.f, 0.f};
#pragma unroll
    for (int i = 0; i < 4; i++)
#pragma unroll
        for (int j = 0; j < 4; j++) acc[i][j] = zf;

    for (int k0 = 0; k0 < K; k0 += 64) {
#pragma unroll
        for (int p = 0; p < 4; p++) {
            const size_t ro = (size_t)(p * 32) * K + k0;
            const int lo_ = (p * 32 + wv4 * 8) * 128;
            gload16(WhB + ro, As_h + lo_);
            gload16(WlB + ro, As_l + lo_);
            gload16(XhB + ro, Bs_h + lo_);
            gload16(XlB + ro, Bs_l + lo_);
        }
        __syncthreads();
#pragma unroll
        for (int kk = 0; kk < 2; kk++) {
            const int akb = kk ? akb1 : akb0;
            s16x8 ah[4], al[4];
#pragma unroll
            for (int mf = 0; mf < 4; mf++) {
                ah[mf] = *(const s16x8*)(As_h + abase + mf * 2048 + akb);
                al[mf] = *(const s16x8*)(As_l + abase + mf * 2048 + akb);
            }
#pragma unroll
            for (int nf = 0; nf < 4; nf++) {
                s16x8 bh = *(const s16x8*)(Bs_h + bbase + nf * 2048 + akb);
                s16x8 bl = *(const s16x8*)(Bs_l + bbase + nf * 2048 + akb);
#pragma unroll
                for (int mf = 0; mf < 4; mf++) {
                    acc[mf][nf] = __builtin_amdgcn_mfma_f32_16x16x32_bf16(ah[mf], bh, acc[mf][nf], 0, 0, 0);
                    acc[mf][nf] = __builtin_amdgcn_mfma_f32_16x16x32_bf16(ah[mf], bl, acc[mf][nf], 0, 0, 0);
                    acc[mf][nf] = __builtin_amdgcn_mfma_f32_16x16x32_bf16(al[mf], bh, acc[mf][nf], 0, 0, 0);
                }
            }
        }
        __syncthreads();
    }

    // epilogue. C/D: col = lane&15 (n), row = (lane>>4)*4 + reg (m)  [m89]
    const int mb = bm + wm, nb = bn + wn;
    float bs[4][4];
#pragma unroll
    for (int mf = 0; mf < 4; mf++)
#pragma unroll
        for (int r = 0; r < 4; r++) bs[mf][r] = bias[mb + mf * 16 + lk * 4 + r];

    if (MODE == 2) {
#pragma unroll
        for (int mf = 0; mf < 4; mf++) {
            const int m0 = mb + mf * 16 + lk * 4;
#pragma unroll
            for (int nf = 0; nf < 4; nf++) {
                const int n = nb + nf * 16 + lrow;
                ushort4 hv, lv;
#pragma unroll
                for (int r = 0; r < 4; r++) {
                    float v = acc[mf][nf][r] + bs[mf][r];
                    v = gelu_exact(v);
                    ushort_t h = f2bf(v);
                    ushort_t lo = f2bf(v - bf2f(h));
                    if (r == 0) { hv.x = h; lv.x = lo; }
                    else if (r == 1) { hv.y = h; lv.y = lo; }
                    else if (r == 2) { hv.z = h; lv.z = lo; }
                    else { hv.w = h; lv.w = lo; }
                }
                *(ushort4*)(outh + ((size_t)b * N + n) * M + m0) = hv;
                *(ushort4*)(outl + ((size_t)b * N + n) * M + m0) = lv;
            }
        }
    } else if (MODE == 3) {
        const float scl = 0.35355339059327373f;
        ushort_t* dstb = (bm < 512) ? outh : outl;
        const int mloc = (bm < 512) ? mb : mb - 512;
#pragma unroll
        for (int mf = 0; mf < 4; mf++) {
            const int m0 = mloc + mf * 16 + lk * 4;
#pragma unroll
            for (int nf = 0; nf < 4; nf++) {
                const int n = nb + nf * 16 + lrow;
                ushort4 hv;
#pragma unroll
                for (int r = 0; r < 4; r++) {
                    float v = (acc[mf][nf][r] + bs[mf][r]) * scl;
                    if (r == 0) hv.x = f2bf(v);
                    else if (r == 1) hv.y = f2bf(v);
                    else if (r == 2) hv.z = f2bf(v);
                    else hv.w = f2bf(v);
                }
                *(ushort4*)(dstb + ((size_t)b * 1024 + n) * 512 + m0) = hv;
            }
        }
    } else if (MODE == 4) {
#pragma unroll
        for (int mf = 0; mf < 4; mf++)
#pragma unroll
            for (int r = 0; r < 4; r++) {
                const int m = mb + mf * 16 + lk * 4 + r;
#pragma unroll
                for (int nf = 0; nf < 4; nf++) {
                    const int n = nb + nf * 16 + lrow;
                    outh[((size_t)b * 512 + m) * 1024 + n] = f2bf(acc[mf][nf][r] + bs[mf][r]);
                }
            }
    } else {
        const size_t obase = (size_t)b * (size_t)M * N;
#pragma unroll
        for (int mf = 0; mf < 4; mf++)
#pragma unroll
            for (int r = 0; r < 4; r++) {
                const int m = mb + mf * 16 + lk * 4 + r;
                const size_t rowo = obase + (size_t)m * N;
#pragma unroll
                for (int nf = 0; nf < 4; nf++) {
                    const int n = nb + nf * 16 + lrow;
                    float v = acc[mf][nf][r] + bs[mf][r];
                    if (MODE == 1) v += res[rowo + n];
                    out[rowo + n] = v;
                }
            }
    }
}

// ================================================================
// kvc GEMM, plain-bf16 MFMA. Wb bf16 [1024][768]; Xb = cn bf16 [b][128][768]
// (t-padded). out[m][n] = sum_k Wb[m][k] Xb[b][n][k] + bias[m].
// Same verified staging/fragment structure as mgemm (BK=64, pre-swizzled
// gload16). Epilogue: m<512 -> kct [b][128][512] (transposed, *scale);
// m>=512 -> vcn [b][512][128]. Pad cols n>=77 zeroed (masked downstream).
__global__ __launch_bounds__(256, 2) void kvc_mfma_k(
    const ushort_t* __restrict__ Wb, const ushort_t* __restrict__ Xb,
    const float* __restrict__ bias, ushort_t* __restrict__ kct,
    ushort_t* __restrict__ vcn)
{
    __shared__ __align__(16) char smem[32768];
    char* As = smem;
    char* Bs = smem + 16384;
    const int K = 768;

    const int b  = blockIdx.z;
    const int bm = blockIdx.y * 128;
    const int tid = threadIdx.x;
    const int l = tid & 63, wv4 = tid >> 6;
    const int lr8 = l >> 3;
    const int lch = (l & 7) ^ lr8;

    const ushort_t* WbB = Wb + (size_t)(bm + wv4 * 8 + lr8) * K + lch * 8;
    const ushort_t* XbB = Xb + ((size_t)b * 128 + wv4 * 8 + lr8) * K + lch * 8;

    const int wm   = (wv4 >> 1) * 64, wn = (wv4 & 1) * 64;
    const int lrow = l & 15, lk = l >> 4;
    const int fswz = (l & 7) << 4;
    const int akb0 = (lk * 16) ^ fswz;
    const int akb1 = (64 + lk * 16) ^ fswz;
    const int abase = (wm + lrow) * 128;
    const int bbase = (wn + lrow) * 128;

    f32x4 acc[4][4];
    const f32x4 zf = {0.f, 0.f, 0.f, 0.f};
#pragma unroll
    for (int i = 0; i < 4; i++)
#pragma unroll
        for (int j = 0; j < 4; j++) acc[i][j] = zf;

    for (int k0 = 0; k0 < K; k0 += 64) {
#pragma unroll
        for (int p = 0; p < 4; p++) {
            const size_t ro = (size_t)(p * 32) * K + k0;
            const int lo_ = (p * 32 + wv4 * 8) * 128;
            gload16(WbB + ro, As + lo_);
            gload16(XbB + ro, Bs + lo_);
        }
        __syncthreads();
#pragma unroll
        for (int kk = 0; kk < 2; kk++) {
            const int akb = kk ? akb1 : akb0;
            s16x8 ah[4];
#pragma unroll
            for (int mf = 0; mf < 4; mf++)
                ah[mf] = *(const s16x8*)(As + abase + mf * 2048 + akb);
#pragma unroll
            for (int nf = 0; nf < 4; nf++) {
                s16x8 bh = *(const s16x8*)(Bs + bbase + nf * 2048 + akb);
#pragma unroll
                for (int mf = 0; mf < 4; mf++)
                    acc[mf][nf] = __builtin_amdgcn_mfma_f32_16x16x32_bf16(ah[mf], bh, acc[mf][nf], 0, 0, 0);
            }
        }
        __syncthreads();
    }

    const int mb = bm + wm;
    float bs[4][4];
#pragma unroll
    for (int mf = 0; mf < 4; mf++)
#pragma unroll
        for (int r = 0; r < 4; r++) bs[mf][r] = bias[mb + mf * 16 + lk * 4 + r];

    if (bm < 512) {
        const float scl = 0.35355339059327373f;
#pragma unroll
        for (int mf = 0; mf < 4; mf++) {
            const int m0 = mb + mf * 16 + lk * 4;
#pragma unroll
            for (int nf = 0; nf < 4; nf++) {
                const int n = wn + nf * 16 + lrow;
                ushort4 hv;
#pragma unroll
                for (int r = 0; r < 4; r++) {
                    float v = (n < 77) ? (acc[mf][nf][r] + bs[mf][r]) * scl : 0.f;
                    if (r == 0) hv.x = f2bf(v);
                    else if (r == 1) hv.y = f2bf(v);
                    else if (r == 2) hv.z = f2bf(v);
                    else hv.w = f2bf(v);
                }
                *(ushort4*)(kct + ((size_t)b * 128 + n) * 512 + m0) = hv;
            }
        }
    } else {
#pragma unroll
        for (int mf = 0; mf < 4; mf++)
#pragma unroll
            for (int r = 0; r < 4; r++) {
                const int m = mb - 512 + mf * 16 + lk * 4 + r;
#pragma unroll
                for (int nf = 0; nf < 4; nf++) {
                    const int n = wn + nf * 16 + lrow;
                    const float v = (n < 77) ? (acc[mf][nf][r] + bs[mf][r]) : 0.f;
                    vcn[((size_t)b * 512 + m) * 128 + n] = f2bf(v);
                }
            }
    }
}

// ================================================================
// MFMA flash attention (bf16 inputs, fp32 softmax/accum). TBLK=64,
// 4 waves x 16 rows, grid 1024 blocks. LDS 24KB. Staging via
// global_load_lds + pre-swizzled source.
template<bool CROSS>
__global__ __launch_bounds__(256) void mattn_k(
    const ushort_t* __restrict__ Qt, const ushort_t* __restrict__ Kt,
    const ushort_t* __restrict__ Vn, float* __restrict__ Ob,
    const int* __restrict__ mask, int spad, int slen,
    size_t k_bs, size_t v_bs, int v_rs)
{
    __shared__ __align__(16) char smem[24576];
    char* QP = smem;
    char* Ks = smem + 8192;
    char* Vs = smem + 16384;

    const int b = blockIdx.z, h = blockIdx.y, tb = blockIdx.x * 64;
    const int tid = threadIdx.x;
    const int l = tid & 63, wv = tid >> 6;
    const int lrow = l & 15, lk = l >> 4;
    const int lsw = (l & 7) << 4;
    const int lr8 = l >> 3, lch = (l & 7) ^ lr8;

    // ---- stage Q (64 x 64) ----
#pragma unroll
    for (int p = 0; p < 2; p++) {
        const int rb = p * 32 + wv * 8;
        gload16(Qt + ((size_t)b * 1024 + tb + rb + lr8) * 512 + h * 64 + lch * 8,
                QP + rb * 128);
    }
    __syncthreads();
    s16x8 qf[2];
#pragma unroll
    for (int ks = 0; ks < 2; ks++) {
        const int row = wv * 16 + lrow;
        qf[ks] = *(const s16x8*)(QP + row * 128 + ((lk * 16 + ks * 64) ^ lsw));
    }

    f32x4 Oa[4];
    const f32x4 zf = {0.f, 0.f, 0.f, 0.f};
    float mo[4], lo[4];
#pragma unroll
    for (int r = 0; r < 4; r++) { mo[r] = -INFINITY; lo[r] = 0.f; Oa[r] = zf; }

    char* Pw = QP + wv * 2048;
    const int nst = spad >> 6;
    for (int st = 0; st < nst; st++) {
        const int s0 = st * 64;
#pragma unroll
        for (int p = 0; p < 2; p++) {
            const int rb = p * 32 + wv * 8;
            gload16(Kt + (size_t)b * k_bs + (size_t)(s0 + rb + lr8) * 512 + h * 64 + lch * 8,
                    Ks + rb * 128);
            gload16(Vn + (size_t)b * v_bs + (size_t)(h * 64 + rb + lr8) * v_rs + s0 + lch * 8,
                    Vs + rb * 128);
        }
        __syncthreads();
        // ---- QK^T ----
        f32x4 sf[4];
#pragma unroll
        for (int nf = 0; nf < 4; nf++) sf[nf] = zf;
#pragma unroll
        for (int ks = 0; ks < 2; ks++) {
            s16x8 bfr[4];
#pragma unroll
            for (int nf = 0; nf < 4; nf++) {
                const int row = nf * 16 + lrow;
                bfr[nf] = *(const s16x8*)(Ks + row * 128 + ((lk * 16 + ks * 64) ^ lsw));
            }
#pragma unroll
            for (int nf = 0; nf < 4; nf++)
                sf[nf] = __builtin_amdgcn_mfma_f32_16x16x32_bf16(qf[ks], bfr[nf], sf[nf], 0, 0, 0);
        }
        bool vld[4];
        if (CROSS) {
#pragma unroll
            for (int nf = 0; nf < 4; nf++) {
                const int s = s0 + nf * 16 + lrow;
                vld[nf] = (s < slen) ? (mask[b * 77 + s] != 0) : false;
            }
        }
        // ---- online softmax; write P (bf16, swizzled) ----
        float alpha[4];
#pragma unroll
        for (int reg = 0; reg < 4; reg++) {
            float v0 = sf[0][reg], v1 = sf[1][reg];
            float v2 = sf[2][reg], v3 = sf[3][reg];
            if (CROSS) {
                v0 = vld[0] ? v0 : -INFINITY;
                v1 = vld[1] ? v1 : -INFINITY;
                v2 = vld[2] ? v2 : -INFINITY;
                v3 = vld[3] ? v3 : -INFINITY;
            }
            float rm = fmaxf(fmaxf(v0, v1), fmaxf(v2, v3));
#pragma unroll
            for (int m = 1; m < 16; m <<= 1) rm = fmaxf(rm, __shfl_xor(rm, m));
            const float mn = fmaxf(mo[reg], rm);
            const float mnf = (mn == -INFINITY) ? 0.f : mn;
            const float al = __expf(mo[reg] - mnf);
            const float p0 = __expf(v0 - mnf), p1 = __expf(v1 - mnf);
            const float p2 = __expf(v2 - mnf), p3 = __expf(v3 - mnf);
            float rs = p0 + p1 + p2 + p3;
#pragma unroll
            for (int m = 1; m < 16; m <<= 1) rs += __shfl_xor(rs, m);
            lo[reg] = lo[reg] * al + rs;
            mo[reg] = mn;
            alpha[reg] = al;
            const int prow = lk * 4 + reg;
            const int rsw = (prow & 7) << 4;
            char* base = Pw + prow * 128;
            *(ushort_t*)(base + ((0 * 32 + lrow * 2) ^ rsw)) = f2bf(p0);
            *(ushort_t*)(base + ((1 * 32 + lrow * 2) ^ rsw)) = f2bf(p1);
            *(ushort_t*)(base + ((2 * 32 + lrow * 2) ^ rsw)) = f2bf(p2);
            *(ushort_t*)(base + ((3 * 32 + lrow * 2) ^ rsw)) = f2bf(p3);
        }
        // ---- rescale O, then PV ----
#pragma unroll
        for (int nf = 0; nf < 4; nf++)
#pragma unroll
            for (int reg = 0; reg < 4; reg++) Oa[nf][reg] *= alpha[reg];
#pragma unroll
        for (int ks = 0; ks < 2; ks++) {
            s16x8 pa = *(const s16x8*)(Pw + lrow * 128 + ((lk * 16 + ks * 64) ^ lsw));
            s16x8 vf[4];
#pragma unroll
            for (int nf = 0; nf < 4; nf++) {
                const int row = nf * 16 + lrow;
                vf[nf] = *(const s16x8*)(Vs + row * 128 + ((lk * 16 + ks * 64) ^ lsw));
            }
#pragma unroll
            for (int nf = 0; nf < 4; nf++)
                Oa[nf] = __builtin_amdgcn_mfma_f32_16x16x32_bf16(pa, vf[nf], Oa[nf], 0, 0, 0);
        }
        __syncthreads();
    }
    float rl[4];
#pragma unroll
    for (int r = 0; r < 4; r++) rl[r] = (lo[r] > 0.f) ? 1.f / lo[r] : 0.f;
#pragma unroll
    for (int reg = 0; reg < 4; reg++) {
        const int t = tb + wv * 16 + lk * 4 + reg;
        float* dr = Ob + ((size_t)b * 1024 + t) * 512 + h * 64 + lrow;
#pragma unroll
        for (int nf = 0; nf < 4; nf++) {
            const float v = Oa[nf][reg] * rl[reg];
            if (CROSS) dr[nf * 16] += v;
            else       dr[nf * 16] = v;
        }
    }
}

// ================================================================
extern "C" void kernel_launch(void* const* d_in, const int* in_sizes, int n_in,
                              void* d_out, int out_size, void* d_ws, size_t ws_size,
                              hipStream_t stream) {
    (void)in_sizes; (void)n_in; (void)out_size; (void)ws_size;
    const float* x        = (const float*)d_in[0];
    const float* cond     = (const float*)d_in[1];
    const int*   cmask    = (const int*)  d_in[2];
    const float* gn_w     = (const float*)d_in[3];
    const float* gn_b     = (const float*)d_in[4];
    const float* qkv_w    = (const float*)d_in[5];
    const float* qkv_b    = (const float*)d_in[6];
    const float* ln_w     = (const float*)d_in[7];
    const float* ln_b     = (const float*)d_in[8];
    const float* kvc_w    = (const float*)d_in[9];
    const float* kvc_b    = (const float*)d_in[10];
    const float* proj_w   = (const float*)d_in[11];
    const float* proj_b   = (const float*)d_in[12];
    const float* ffn_gn_w = (const float*)d_in[13];
    const float* ffn_gn_b = (const float*)d_in[14];
    const float* ffn_w1   = (const float*)d_in[15];
    const float* ffn_b1   = (const float*)d_in[16];
    const float* ffn_w2   = (const float*)d_in[17];
    const float* ffn_b2   = (const float*)d_in[18];

    // Workspace (float units), total 28,801,024 fl ~= 115.2 MiB (unchanged).
    float* ws    = (float*)d_ws;
    float* gn1_s = ws;                  float* gn1_b = ws + 4096;
    float* gn2_s = ws + 8192;           float* gn2_b = ws + 12288;
    ushort_t* cnb = (ushort_t*)(ws + 16384);     // [8][128][768] bf16 (393216 fl slot)
    float* x1    = ws + 489472;         // 4194304 fl; wk_bf borrows it pre-proj
    ushort_t* wk_bf = (ushort_t*)x1;             // [1024][768] bf16 (dead when proj writes x1)
    ushort_t* ts_h = (ushort_t*)(ws + 4683776);  // split activation slot
    ushort_t* ts_l = ts_h + 4194304;
    ushort_t* qt  = (ushort_t*)(ws + 8878080);   // [8][1024][512] bf16
    ushort_t* kt  = qt + 4194304;                // [8][1024][512]
    ushort_t* vn  = kt + 4194304;                // [8][512][1024]
    float*    hb  = ws + 15169536;               // [8][1024][512] fp32
    ushort_t* kct = (ushort_t*)(ws + 19363840);  // [8][128][512]
    ushort_t* vcn = kct + 524288;                // [8][512][128]
    ushort_t* yt_h = (ushort_t*)(ws + 8878080);  // [8][1024][2048] x2 (overlay)
    ushort_t* yt_l = yt_h + 16777216;
    ushort_t* wq_h = (ushort_t*)(ws + 25655296);
    ushort_t* wq_l = wq_h + 786432;
    ushort_t* wp_h = wq_l + 786432;
    ushort_t* wp_l = wp_h + 262144;
    ushort_t* w1_h = wp_l + 262144;
    ushort_t* w1_l = w1_h + 1048576;
    ushort_t* w2_h = w1_l + 1048576;
    ushort_t* w2_l = w2_h + 1048576;

    // 1) GN1 stats; weight conversions
    gn_stats_k<<<256, 256, 0, stream>>>(x, gn_w, gn_b, gn1_s, gn1_b);
    wsplit_k<<<768, 256, 0, stream>>>(qkv_w, wq_h, wq_l, 196608);
    wsplit_k<<<256, 256, 0, stream>>>(proj_w, wp_h, wp_l, 65536);
    wsplit_k<<<1024, 256, 0, stream>>>(ffn_w1, w1_h, w1_l, 262144);
    wsplit_k<<<1024, 256, 0, stream>>>(ffn_w2, w2_h, w2_l, 262144);
    wcast_k<<<768, 256, 0, stream>>>(kvc_w, wk_bf, 196608);
    // 2) xt1 = T(GN1(x)) split
    tsplit_k<true><<<dim3(16, 8, 8), 256, 0, stream>>>(x, gn1_s, gn1_b, ts_h, ts_l, 512, 1024);
    // 3) qkv GEMM: q/k rows -> qt/kt (transposed bf16, *scale); v rows -> vn
    mgemm_k<3><<<dim3(8, 8, 8), 256, 0, stream>>>(
        wq_h, wq_l, ts_h, ts_l, qkv_b, nullptr, nullptr, qt, kt, 1024, 512, 1024);
    mgemm_k<4><<<dim3(8, 4, 8), 256, 0, stream>>>(
        wq_h + (size_t)1024 * 512, wq_l + (size_t)1024 * 512, ts_h, ts_l,
        qkv_b + 1024, nullptr, nullptr, vn, nullptr, 512, 512, 1024);
    // 4) self-attention (MFMA) -> hb [b][t][c]
    mattn_k<false><<<dim3(16, 8, 8), 256, 0, stream>>>(
        qt, kt, vn, hb, nullptr, 1024, 1024,
        (size_t)1024 * 512, (size_t)512 * 1024, 1024);
    // 5) LN(cond) bf16 padded; kvc MFMA GEMM -> kct/vcn
    ln_bf_k<<<1024, 256, 0, stream>>>(cond, ln_w, ln_b, cnb);
    kvc_mfma_k<<<dim3(1, 8, 8), 256, 0, stream>>>(wk_bf, cnb, kvc_b, kct, vcn);
    // 6) cross-attention (MFMA, masked), accumulate into hb
    mattn_k<true><<<dim3(16, 8, 8), 256, 0, stream>>>(
        qt, kct, vcn, hb, cmask, 128, 77,
        (size_t)128 * 512, (size_t)512 * 128, 128);
    // 7) split hb (already [b][t][c] = [N][K]) -> ts; proj GEMM (writes x1,
    //    wk_bf dead by now)
    wsplit_k<<<1024, 256, 0, stream>>>(hb, ts_h, ts_l, 1048576);
    mgemm_k<1><<<dim3(8, 4, 8), 256, 0, stream>>>(
        wp_h, wp_l, ts_h, ts_l, proj_b, x, x1, nullptr, nullptr, 512, 512, 1024);
    // 8) GN2; x1t split; ffn1 (gelu, transposed bf16 out); ffn2 (+res)
    gn_stats_k<<<256, 256, 0, stream>>>(x1, ffn_gn_w, ffn_gn_b, gn2_s, gn2_b);
    tsplit_k<true><<<dim3(16, 8, 8), 256, 0, stream>>>(x1, gn2_s, gn2_b, ts_h, ts_l, 512, 1024);
    mgemm_k<2><<<dim3(8, 16, 8), 256, 0, stream>>>(
        w1_h, w1_l, ts_h, ts_l, ffn_b1, nullptr, nullptr, yt_h, yt_l, 2048, 512, 1024);
    mgemm_k<1><<<dim3(8, 4, 8), 256, 0, stream>>>(
        w2_h, w2_l, yt_h, yt_l, ffn_b2, x1, (float*)d_out, nullptr, nullptr, 512, 2048, 1024);
}

// Round 8
// 394.895 us; speedup vs baseline: 2.1311x; 1.1076x over previous
//
#include <hip/hip_runtime.h>
#include <math.h>

// B=8, C=512, L=1024, heads=8x64, GROUPS=32, cond Lc=77 D=768. fp32 in/out.
// GEMMs: bf16 MFMA, per-GEMM precision (VAR): 1 = Wh*Xh+Wh*Xl, 2 = Wh*Xh+Wl*Xh.
// Coalesced LDS-staged epilogues for bf16 outputs. Attention: bf16 MFMA flash.

typedef float f32x4 __attribute__((ext_vector_type(4)));
typedef short s16x8 __attribute__((ext_vector_type(8)));
typedef unsigned short ushort_t;

typedef const void __attribute__((address_space(1)))* gas_ptr;
typedef void __attribute__((address_space(3)))* las_ptr;

__device__ __forceinline__ void gload16(const void* g, void* l) {
    __builtin_amdgcn_global_load_lds((gas_ptr)g, (las_ptr)l, 16, 0, 0);
}

__device__ __forceinline__ float gelu_exact(float v) {
    return 0.5f * v * (1.0f + erff(v * 0.70710678118654752f));
}
__device__ __forceinline__ ushort_t f2bf(float f) {
    unsigned int u = __float_as_uint(f);
    return (ushort_t)((u + 0x7FFFu + ((u >> 16) & 1u)) >> 16);
}
__device__ __forceinline__ float bf2f(ushort_t h) {
    return __uint_as_float(((unsigned int)h) << 16);
}

// ================================================================
__global__ __launch_bounds__(256) void gn_stats_k(
    const float* __restrict__ x, const float* __restrict__ gw,
    const float* __restrict__ gb, float* __restrict__ oscl, float* __restrict__ obia)
{
    const int blk = blockIdx.x;
    const int b = blk >> 5, g = blk & 31;
    const float4* base = (const float4*)(x + ((size_t)b * 512 + (size_t)g * 16) * 1024);
    float s = 0.f, sq = 0.f;
    for (int i = threadIdx.x; i < 4096; i += 256) {
        float4 v = base[i];
        s  += v.x + v.y + v.z + v.w;
        sq += v.x * v.x + v.y * v.y + v.z * v.z + v.w * v.w;
    }
#pragma unroll
    for (int m = 32; m >= 1; m >>= 1) { s += __shfl_xor(s, m); sq += __shfl_xor(sq, m); }
    __shared__ float ls[4], lq[4];
    const int wid = threadIdx.x >> 6;
    if ((threadIdx.x & 63) == 0) { ls[wid] = s; lq[wid] = sq; }
    __syncthreads();
    if (threadIdx.x == 0) {
        float S = ls[0] + ls[1] + ls[2] + ls[3];
        float Q = lq[0] + lq[1] + lq[2] + lq[3];
        float mean = S * (1.f / 16384.f);
        float var  = Q * (1.f / 16384.f) - mean * mean;
        float istd = rsqrtf(var + 1e-5f);
#pragma unroll
        for (int cc = 0; cc < 16; cc++) {
            int c = g * 16 + cc;
            float sc = gw[c] * istd;
            oscl[b * 512 + c] = sc;
            obia[b * 512 + c] = gb[c] - mean * sc;
        }
    }
}

// ================================================================
// LayerNorm over D=768 -> bf16 cn [b][128][768] (t-rows 77..127 zeroed).
__global__ __launch_bounds__(256) void ln_bf_k(
    const float* __restrict__ cond, const float* __restrict__ lw,
    const float* __restrict__ lb, ushort_t* __restrict__ out)
{
    const int blk = blockIdx.x;
    const int b = blk >> 7, t = blk & 127;
    ushort_t* orow = out + ((size_t)b * 128 + t) * 768;
    if (t >= 77) {
#pragma unroll
        for (int p = 0; p < 3; p++) orow[threadIdx.x + p * 256] = 0;
        return;
    }
    const float* row = cond + ((size_t)b * 77 + t) * 768;
    float v[3];
    float s = 0.f, sq = 0.f;
#pragma unroll
    for (int p = 0; p < 3; p++) {
        v[p] = row[threadIdx.x + p * 256];
        s += v[p]; sq += v[p] * v[p];
    }
#pragma unroll
    for (int m = 32; m >= 1; m >>= 1) { s += __shfl_xor(s, m); sq += __shfl_xor(sq, m); }
    __shared__ float ls[4], lq[4], stat[2];
    const int wid = threadIdx.x >> 6;
    if ((threadIdx.x & 63) == 0) { ls[wid] = s; lq[wid] = sq; }
    __syncthreads();
    if (threadIdx.x == 0) {
        float S = ls[0] + ls[1] + ls[2] + ls[3];
        float Q = lq[0] + lq[1] + lq[2] + lq[3];
        float mean = S * (1.f / 768.f);
        float var  = Q * (1.f / 768.f) - mean * mean;
        stat[0] = mean; stat[1] = rsqrtf(var + 1e-5f);
    }
    __syncthreads();
    const float mean = stat[0], istd = stat[1];
#pragma unroll
    for (int p = 0; p < 3; p++) {
        int d = threadIdx.x + p * 256;
        orow[d] = f2bf((v[p] - mean) * istd * lw[d] + lb[d]);
    }
}

// ================================================================
// fp32 -> (hi, lo) bf16 split (ffn2 weight, hb).
__global__ __launch_bounds__(256) void wsplit_k(
    const float* __restrict__ w, ushort_t* __restrict__ oh, ushort_t* __restrict__ ol, int n4)
{
    for (int i = blockIdx.x * 256 + threadIdx.x; i < n4; i += gridDim.x * 256) {
        float4 v = ((const float4*)w)[i];
        ushort4 h, l;
        h.x = f2bf(v.x); l.x = f2bf(v.x - bf2f(h.x));
        h.y = f2bf(v.y); l.y = f2bf(v.y - bf2f(h.y));
        h.z = f2bf(v.z); l.z = f2bf(v.z - bf2f(h.z));
        h.w = f2bf(v.w); l.w = f2bf(v.w - bf2f(h.w));
        ((ushort4*)oh)[i] = h;
        ((ushort4*)ol)[i] = l;
    }
}

// ================================================================
// fp32 -> bf16 cast (hi only), elementwise.
__global__ __launch_bounds__(256) void wcast_k(
    const float* __restrict__ w, ushort_t* __restrict__ oh, int n4)
{
    for (int i = blockIdx.x * 256 + threadIdx.x; i < n4; i += gridDim.x * 256) {
        float4 v = ((const float4*)w)[i];
        ushort4 h;
        h.x = f2bf(v.x); h.y = f2bf(v.y); h.z = f2bf(v.z); h.w = f2bf(v.w);
        ((ushort4*)oh)[i] = h;
    }
}

// ================================================================
// Transpose + split (+ optional fused GN scale/bias): [b][R][C] -> [b][C][R].
template<bool SB>
__global__ __launch_bounds__(256) void tsplit_k(
    const float* __restrict__ in, const float* __restrict__ scl,
    const float* __restrict__ bia, ushort_t* __restrict__ oh,
    ushort_t* __restrict__ ol, int R, int C)
{
    __shared__ ushort_t Lh[64][68], Ll[64][68];
    const int b = blockIdx.z, r0 = blockIdx.y * 64, c0 = blockIdx.x * 64;
    const int tid = threadIdx.x;
#pragma unroll
    for (int p = 0; p < 4; p++) {
        const int q = tid + p * 256;
        const int rr = q >> 4, cc4 = (q & 15) * 4;
        float4 v = *(const float4*)(in + ((size_t)b * R + r0 + rr) * C + c0 + cc4);
        if (SB) {
            const float s = scl[b * R + r0 + rr], o = bia[b * R + r0 + rr];
            v.x = v.x * s + o; v.y = v.y * s + o; v.z = v.z * s + o; v.w = v.w * s + o;
        }
        ushort4 h, l;
        h.x = f2bf(v.x); l.x = f2bf(v.x - bf2f(h.x));
        h.y = f2bf(v.y); l.y = f2bf(v.y - bf2f(h.y));
        h.z = f2bf(v.z); l.z = f2bf(v.z - bf2f(h.z));
        h.w = f2bf(v.w); l.w = f2bf(v.w - bf2f(h.w));
        *(ushort4*)&Lh[rr][cc4] = h;
        *(ushort4*)&Ll[rr][cc4] = l;
    }
    __syncthreads();
#pragma unroll
    for (int p = 0; p < 4; p++) {
        const int q = tid + p * 256;
        const int nn = q >> 4, rr4 = (q & 15) * 4;
        ushort4 h, l;
        h.x = Lh[rr4 + 0][nn]; h.y = Lh[rr4 + 1][nn];
        h.z = Lh[rr4 + 2][nn]; h.w = Lh[rr4 + 3][nn];
        l.x = Ll[rr4 + 0][nn]; l.y = Ll[rr4 + 1][nn];
        l.z = Ll[rr4 + 2][nn]; l.w = Ll[rr4 + 3][nn];
        *(ushort4*)(oh + ((size_t)b * C + c0 + nn) * R + r0 + rr4) = h;
        *(ushort4*)(ol + ((size_t)b * C + c0 + nn) * R + r0 + rr4) = l;
    }
}

// ================================================================
// MFMA GEMM. W [M][K] bf16 (hi[, lo]); X [b][N][K] bf16 (hi[, lo]).
// Tile 128m x (NF*32)n x BK64, 4 waves, wave tile 64 x (NF*16).
// VAR bit0: + Wh*Xl (X split). VAR bit1: + Wl*Xh (W split).
// MODE 1: +bias+res, fp32 [b][M][N] direct (64B-sector coalesced).
// MODE 2: +bias+gelu -> bf16 [b][N][M] via LDS-coalesced epilogue.
// MODE 3: +bias, *attn-scale -> bf16 [b][1024][512] qt (bm<512) / kt.
// MODE 4: +bias -> bf16 [b][M][N] (v), LDS-coalesced.
// Staging via global_load_lds 16B, T2 swizzle by pre-XORed SOURCE chunk.
template<int MODE, int NF, int VAR>
__global__ __launch_bounds__(256, 2) void mgemm_k(
    const ushort_t* __restrict__ Wh, const ushort_t* __restrict__ Wl,
    const ushort_t* __restrict__ Xh, const ushort_t* __restrict__ Xl,
    const float* __restrict__ bias, const float* __restrict__ res,
    float* __restrict__ out, ushort_t* __restrict__ outh, ushort_t* __restrict__ outl,
    int M, int K, int N)
{
    constexpr int ASL   = (VAR & 2) ? 16384 : 0;
    constexpr int BSH   = NF * 32 * 128;
    constexpr int BSL   = (VAR & 1) ? BSH : 0;
    constexpr int STAGE = 16384 + ASL + BSH + BSL;
    constexpr int TSZ   = (MODE == 1) ? 0 : 128 * 136 * 2;
    constexpr int SMEM  = STAGE > TSZ ? STAGE : TSZ;
    __shared__ __align__(16) char smem[SMEM];
    char* As_h = smem;
    char* As_l = smem + 16384;           // valid iff VAR&2
    char* Bs_h = smem + 16384 + ASL;
    char* Bs_l = Bs_h + BSH;             // valid iff VAR&1

    const int b  = blockIdx.z;
    const int bm = blockIdx.y * 128, bn = blockIdx.x * (NF * 32);
    const int tid = threadIdx.x;
    const int l = tid & 63, wv4 = tid >> 6;
    const int lr8 = l >> 3;
    const int lch = (l & 7) ^ lr8;       // pre-swizzled source chunk

    const size_t wrow = (size_t)(bm + wv4 * 8 + lr8);
    const size_t xrow = (size_t)(bn + wv4 * 8 + lr8);
    const ushort_t* WhB = Wh + wrow * K + lch * 8;
    const ushort_t* WlB = (VAR & 2) ? (Wl + wrow * K + lch * 8) : nullptr;
    const ushort_t* XhB = Xh + ((size_t)b * N + xrow) * K + lch * 8;
    const ushort_t* XlB = (VAR & 1) ? (Xl + ((size_t)b * N + xrow) * K + lch * 8) : nullptr;

    const int wm   = (wv4 >> 1) * 64, wn = (wv4 & 1) * (NF * 16);
    const int lrow = l & 15, lk = l >> 4;
    const int fswz = (l & 7) << 4;
    const int akb0 = (lk * 16) ^ fswz;
    const int akb1 = (64 + lk * 16) ^ fswz;
    const int abase = (wm + lrow) * 128;
    const int bbase = (wn + lrow) * 128;

    f32x4 acc[4][NF];
    const f32x4 zf = {0.f, 0.f, 0.f, 0.f};
#pragma unroll
    for (int i = 0; i < 4; i++)
#pragma unroll
        for (int j = 0; j < NF; j++) acc[i][j] = zf;

    for (int k0 = 0; k0 < K; k0 += 64) {
#pragma unroll
        for (int p = 0; p < 4; p++) {
            const size_t ro = (size_t)(p * 32) * K + k0;
            const int lo_ = (p * 32 + wv4 * 8) * 128;
            gload16(WhB + ro, As_h + lo_);
            if (VAR & 2) gload16(WlB + ro, As_l + lo_);
        }
#pragma unroll
        for (int p = 0; p < NF; p++) {
            const size_t ro = (size_t)(p * 32) * K + k0;
            const int lo_ = (p * 32 + wv4 * 8) * 128;
            gload16(XhB + ro, Bs_h + lo_);
            if (VAR & 1) gload16(XlB + ro, Bs_l + lo_);
        }
        __syncthreads();
#pragma unroll
        for (int kk = 0; kk < 2; kk++) {
            const int akb = kk ? akb1 : akb0;
            s16x8 ah[4], al[4];
#pragma unroll
            for (int mf = 0; mf < 4; mf++) {
                ah[mf] = *(const s16x8*)(As_h + abase + mf * 2048 + akb);
                if (VAR & 2) al[mf] = *(const s16x8*)(As_l + abase + mf * 2048 + akb);
            }
#pragma unroll
            for (int nf = 0; nf < NF; nf++) {
                s16x8 bh = *(const s16x8*)(Bs_h + bbase + nf * 2048 + akb);
                s16x8 bl;
                if (VAR & 1) bl = *(const s16x8*)(Bs_l + bbase + nf * 2048 + akb);
#pragma unroll
                for (int mf = 0; mf < 4; mf++) {
                    acc[mf][nf] = __builtin_amdgcn_mfma_f32_16x16x32_bf16(ah[mf], bh, acc[mf][nf], 0, 0, 0);
                    if (VAR & 1)
                        acc[mf][nf] = __builtin_amdgcn_mfma_f32_16x16x32_bf16(ah[mf], bl, acc[mf][nf], 0, 0, 0);
                    if (VAR & 2)
                        acc[mf][nf] = __builtin_amdgcn_mfma_f32_16x16x32_bf16(al[mf], bh, acc[mf][nf], 0, 0, 0);
                }
            }
        }
        __syncthreads();
    }

    // ---- epilogue. C/D: col(n) = lane&15, row(m) = lk*4 + reg  [m89] ----
    const int mb = bm + wm, nb = bn + wn;
    float bs[4][4];
#pragma unroll
    for (int mf = 0; mf < 4; mf++)
#pragma unroll
        for (int r = 0; r < 4; r++) bs[mf][r] = bias[mb + mf * 16 + lk * 4 + r];

    if (MODE == 1) {
        const size_t obase = (size_t)b * (size_t)M * N;
#pragma unroll
        for (int mf = 0; mf < 4; mf++)
#pragma unroll
            for (int r = 0; r < 4; r++) {
                const int m = mb + mf * 16 + lk * 4 + r;
                const size_t rowo = obase + (size_t)m * N;
#pragma unroll
                for (int nf = 0; nf < NF; nf++) {
                    const int n = nb + nf * 16 + lrow;
                    out[rowo + n] = acc[mf][nf][r] + bs[mf][r] + res[rowo + n];
                }
            }
    } else {
        // stage bf16 tile in LDS (pitch 136 ushorts), then coalesced write
        ushort_t* T = (ushort_t*)smem;
        const float scl = 0.35355339059327373f;
#pragma unroll
        for (int mf = 0; mf < 4; mf++) {
#pragma unroll
            for (int nf = 0; nf < NF; nf++) {
                const int nl = wn + nf * 16 + lrow;
                const int ml = wm + mf * 16 + lk * 4;
                if (MODE == 2 || MODE == 3) {
                    ushort4 hv;
#pragma unroll
                    for (int r = 0; r < 4; r++) {
                        float v = acc[mf][nf][r] + bs[mf][r];
                        if (MODE == 2) v = gelu_exact(v);
                        else v *= scl;
                        if (r == 0) hv.x = f2bf(v);
                        else if (r == 1) hv.y = f2bf(v);
                        else if (r == 2) hv.z = f2bf(v);
                        else hv.w = f2bf(v);
                    }
                    *(ushort4*)&T[nl * 136 + ml] = hv;
                } else { // MODE 4: T[m][n]
#pragma unroll
                    for (int r = 0; r < 4; r++)
                        T[(ml + r) * 136 + nl] = f2bf(acc[mf][nf][r] + bs[mf][r]);
                }
            }
        }
        __syncthreads();
        const int ch = tid & 15;
        ushort_t* dstb = outh;
        int mloc = bm;
        if (MODE == 3 && bm >= 512) { dstb = outl; mloc = bm - 512; }
#pragma unroll
        for (int ps = 0; ps < 8; ps++) {
            const int row = ps * 16 + (tid >> 4);
            s16x8 v = *(const s16x8*)&T[row * 136 + ch * 8];
            size_t ga;
            if (MODE == 2)      ga = ((size_t)b * N + bn + row) * M + bm + ch * 8;
            else if (MODE == 3) ga = ((size_t)b * 1024 + bn + row) * 512 + mloc + ch * 8;
            else                ga = ((size_t)b * 512 + bm + row) * 1024 + bn + ch * 8;
            *(s16x8*)(dstb + ga) = v;
        }
    }
}

// ================================================================
// kvc GEMM, plain-bf16 MFMA (unchanged from round 6; ~5 us).
__global__ __launch_bounds__(256, 2) void kvc_mfma_k(
    const ushort_t* __restrict__ Wb, const ushort_t* __restrict__ Xb,
    const float* __restrict__ bias, ushort_t* __restrict__ kct,
    ushort_t* __restrict__ vcn)
{
    __shared__ __align__(16) char smem[32768];
    char* As = smem;
    char* Bs = smem + 16384;
    const int K = 768;

    const int b  = blockIdx.z;
    const int bm = blockIdx.y * 128;
    const int tid = threadIdx.x;
    const int l = tid & 63, wv4 = tid >> 6;
    const int lr8 = l >> 3;
    const int lch = (l & 7) ^ lr8;

    const ushort_t* WbB = Wb + (size_t)(bm + wv4 * 8 + lr8) * K + lch * 8;
    const ushort_t* XbB = Xb + ((size_t)b * 128 + wv4 * 8 + lr8) * K + lch * 8;

    const int wm   = (wv4 >> 1) * 64, wn = (wv4 & 1) * 64;
    const int lrow = l & 15, lk = l >> 4;
    const int fswz = (l & 7) << 4;
    const int akb0 = (lk * 16) ^ fswz;
    const int akb1 = (64 + lk * 16) ^ fswz;
    const int abase = (wm + lrow) * 128;
    const int bbase = (wn + lrow) * 128;

    f32x4 acc[4][4];
    const f32x4 zf = {0.f, 0.f, 0.f, 0.f};
#pragma unroll
    for (int i = 0; i < 4; i++)
#pragma unroll
        for (int j = 0; j < 4; j++) acc[i][j] = zf;

    for (int k0 = 0; k0 < K; k0 += 64) {
#pragma unroll
        for (int p = 0; p < 4; p++) {
            const size_t ro = (size_t)(p * 32) * K + k0;
            const int lo_ = (p * 32 + wv4 * 8) * 128;
            gload16(WbB + ro, As + lo_);
            gload16(XbB + ro, Bs + lo_);
        }
        __syncthreads();
#pragma unroll
        for (int kk = 0; kk < 2; kk++) {
            const int akb = kk ? akb1 : akb0;
            s16x8 ah[4];
#pragma unroll
            for (int mf = 0; mf < 4; mf++)
                ah[mf] = *(const s16x8*)(As + abase + mf * 2048 + akb);
#pragma unroll
            for (int nf = 0; nf < 4; nf++) {
                s16x8 bh = *(const s16x8*)(Bs + bbase + nf * 2048 + akb);
#pragma unroll
                for (int mf = 0; mf < 4; mf++)
                    acc[mf][nf] = __builtin_amdgcn_mfma_f32_16x16x32_bf16(ah[mf], bh, acc[mf][nf], 0, 0, 0);
            }
        }
        __syncthreads();
    }

    const int mb = bm + wm;
    float bs[4][4];
#pragma unroll
    for (int mf = 0; mf < 4; mf++)
#pragma unroll
        for (int r = 0; r < 4; r++) bs[mf][r] = bias[mb + mf * 16 + lk * 4 + r];

    if (bm < 512) {
        const float scl = 0.35355339059327373f;
#pragma unroll
        for (int mf = 0; mf < 4; mf++) {
            const int m0 = mb + mf * 16 + lk * 4;
#pragma unroll
            for (int nf = 0; nf < 4; nf++) {
                const int n = wn + nf * 16 + lrow;
                ushort4 hv;
#pragma unroll
                for (int r = 0; r < 4; r++) {
                    float v = (n < 77) ? (acc[mf][nf][r] + bs[mf][r]) * scl : 0.f;
                    if (r == 0) hv.x = f2bf(v);
                    else if (r == 1) hv.y = f2bf(v);
                    else if (r == 2) hv.z = f2bf(v);
                    else hv.w = f2bf(v);
                }
                *(ushort4*)(kct + ((size_t)b * 128 + n) * 512 + m0) = hv;
            }
        }
    } else {
#pragma unroll
        for (int mf = 0; mf < 4; mf++)
#pragma unroll
            for (int r = 0; r < 4; r++) {
                const int m = mb - 512 + mf * 16 + lk * 4 + r;
#pragma unroll
                for (int nf = 0; nf < 4; nf++) {
                    const int n = wn + nf * 16 + lrow;
                    const float v = (n < 77) ? (acc[mf][nf][r] + bs[mf][r]) : 0.f;
                    vcn[((size_t)b * 512 + m) * 128 + n] = f2bf(v);
                }
            }
    }
}

// ================================================================
// MFMA flash attention (unchanged from round 6).
template<bool CROSS>
__global__ __launch_bounds__(256) void mattn_k(
    const ushort_t* __restrict__ Qt, const ushort_t* __restrict__ Kt,
    const ushort_t* __restrict__ Vn, float* __restrict__ Ob,
    const int* __restrict__ mask, int spad, int slen,
    size_t k_bs, size_t v_bs, int v_rs)
{
    __shared__ __align__(16) char smem[24576];
    char* QP = smem;
    char* Ks = smem + 8192;
    char* Vs = smem + 16384;

    const int b = blockIdx.z, h = blockIdx.y, tb = blockIdx.x * 64;
    const int tid = threadIdx.x;
    const int l = tid & 63, wv = tid >> 6;
    const int lrow = l & 15, lk = l >> 4;
    const int lsw = (l & 7) << 4;
    const int lr8 = l >> 3, lch = (l & 7) ^ lr8;

#pragma unroll
    for (int p = 0; p < 2; p++) {
        const int rb = p * 32 + wv * 8;
        gload16(Qt + ((size_t)b * 1024 + tb + rb + lr8) * 512 + h * 64 + lch * 8,
                QP + rb * 128);
    }
    __syncthreads();
    s16x8 qf[2];
#pragma unroll
    for (int ks = 0; ks < 2; ks++) {
        const int row = wv * 16 + lrow;
        qf[ks] = *(const s16x8*)(QP + row * 128 + ((lk * 16 + ks * 64) ^ lsw));
    }

    f32x4 Oa[4];
    const f32x4 zf = {0.f, 0.f, 0.f, 0.f};
    float mo[4], lo[4];
#pragma unroll
    for (int r = 0; r < 4; r++) { mo[r] = -INFINITY; lo[r] = 0.f; Oa[r] = zf; }

    char* Pw = QP + wv * 2048;
    const int nst = spad >> 6;
    for (int st = 0; st < nst; st++) {
        const int s0 = st * 64;
#pragma unroll
        for (int p = 0; p < 2; p++) {
            const int rb = p * 32 + wv * 8;
            gload16(Kt + (size_t)b * k_bs + (size_t)(s0 + rb + lr8) * 512 + h * 64 + lch * 8,
                    Ks + rb * 128);
            gload16(Vn + (size_t)b * v_bs + (size_t)(h * 64 + rb + lr8) * v_rs + s0 + lch * 8,
                    Vs + rb * 128);
        }
        __syncthreads();
        f32x4 sf[4];
#pragma unroll
        for (int nf = 0; nf < 4; nf++) sf[nf] = zf;
#pragma unroll
        for (int ks = 0; ks < 2; ks++) {
            s16x8 bfr[4];
#pragma unroll
            for (int nf = 0; nf < 4; nf++) {
                const int row = nf * 16 + lrow;
                bfr[nf] = *(const s16x8*)(Ks + row * 128 + ((lk * 16 + ks * 64) ^ lsw));
            }
#pragma unroll
            for (int nf = 0; nf < 4; nf++)
                sf[nf] = __builtin_amdgcn_mfma_f32_16x16x32_bf16(qf[ks], bfr[nf], sf[nf], 0, 0, 0);
        }
        bool vld[4];
        if (CROSS) {
#pragma unroll
            for (int nf = 0; nf < 4; nf++) {
                const int s = s0 + nf * 16 + lrow;
                vld[nf] = (s < slen) ? (mask[b * 77 + s] != 0) : false;
            }
        }
        float alpha[4];
#pragma unroll
        for (int reg = 0; reg < 4; reg++) {
            float v0 = sf[0][reg], v1 = sf[1][reg];
            float v2 = sf[2][reg], v3 = sf[3][reg];
            if (CROSS) {
                v0 = vld[0] ? v0 : -INFINITY;
                v1 = vld[1] ? v1 : -INFINITY;
                v2 = vld[2] ? v2 : -INFINITY;
                v3 = vld[3] ? v3 : -INFINITY;
            }
            float rm = fmaxf(fmaxf(v0, v1), fmaxf(v2, v3));
#pragma unroll
            for (int m = 1; m < 16; m <<= 1) rm = fmaxf(rm, __shfl_xor(rm, m));
            const float mn = fmaxf(mo[reg], rm);
            const float mnf = (mn == -INFINITY) ? 0.f : mn;
            const float al = __expf(mo[reg] - mnf);
            const float p0 = __expf(v0 - mnf), p1 = __expf(v1 - mnf);
            const float p2 = __expf(v2 - mnf), p3 = __expf(v3 - mnf);
            float rs = p0 + p1 + p2 + p3;
#pragma unroll
            for (int m = 1; m < 16; m <<= 1) rs += __shfl_xor(rs, m);
            lo[reg] = lo[reg] * al + rs;
            mo[reg] = mn;
            alpha[reg] = al;
            const int prow = lk * 4 + reg;
            const int rsw = (prow & 7) << 4;
            char* base = Pw + prow * 128;
            *(ushort_t*)(base + ((0 * 32 + lrow * 2) ^ rsw)) = f2bf(p0);
            *(ushort_t*)(base + ((1 * 32 + lrow * 2) ^ rsw)) = f2bf(p1);
            *(ushort_t*)(base + ((2 * 32 + lrow * 2) ^ rsw)) = f2bf(p2);
            *(ushort_t*)(base + ((3 * 32 + lrow * 2) ^ rsw)) = f2bf(p3);
        }
#pragma unroll
        for (int nf = 0; nf < 4; nf++)
#pragma unroll
            for (int reg = 0; reg < 4; reg++) Oa[nf][reg] *= alpha[reg];
#pragma unroll
        for (int ks = 0; ks < 2; ks++) {
            s16x8 pa = *(const s16x8*)(Pw + lrow * 128 + ((lk * 16 + ks * 64) ^ lsw));
            s16x8 vf[4];
#pragma unroll
            for (int nf = 0; nf < 4; nf++) {
                const int row = nf * 16 + lrow;
                vf[nf] = *(const s16x8*)(Vs + row * 128 + ((lk * 16 + ks * 64) ^ lsw));
            }
#pragma unroll
            for (int nf = 0; nf < 4; nf++)
                Oa[nf] = __builtin_amdgcn_mfma_f32_16x16x32_bf16(pa, vf[nf], Oa[nf], 0, 0, 0);
        }
        __syncthreads();
    }
    float rl[4];
#pragma unroll
    for (int r = 0; r < 4; r++) rl[r] = (lo[r] > 0.f) ? 1.f / lo[r] : 0.f;
#pragma unroll
    for (int reg = 0; reg < 4; reg++) {
        const int t = tb + wv * 16 + lk * 4 + reg;
        float* dr = Ob + ((size_t)b * 1024 + t) * 512 + h * 64 + lrow;
#pragma unroll
        for (int nf = 0; nf < 4; nf++) {
            const float v = Oa[nf][reg] * rl[reg];
            if (CROSS) dr[nf * 16] += v;
            else       dr[nf * 16] = v;
        }
    }
}

// ================================================================
extern "C" void kernel_launch(void* const* d_in, const int* in_sizes, int n_in,
                              void* d_out, int out_size, void* d_ws, size_t ws_size,
                              hipStream_t stream) {
    (void)in_sizes; (void)n_in; (void)out_size; (void)ws_size;
    const float* x        = (const float*)d_in[0];
    const float* cond     = (const float*)d_in[1];
    const int*   cmask    = (const int*)  d_in[2];
    const float* gn_w     = (const float*)d_in[3];
    const float* gn_b     = (const float*)d_in[4];
    const float* qkv_w    = (const float*)d_in[5];
    const float* qkv_b    = (const float*)d_in[6];
    const float* ln_w     = (const float*)d_in[7];
    const float* ln_b     = (const float*)d_in[8];
    const float* kvc_w    = (const float*)d_in[9];
    const float* kvc_b    = (const float*)d_in[10];
    const float* proj_w   = (const float*)d_in[11];
    const float* proj_b   = (const float*)d_in[12];
    const float* ffn_gn_w = (const float*)d_in[13];
    const float* ffn_gn_b = (const float*)d_in[14];
    const float* ffn_w1   = (const float*)d_in[15];
    const float* ffn_b1   = (const float*)d_in[16];
    const float* ffn_w2   = (const float*)d_in[17];
    const float* ffn_b2   = (const float*)d_in[18];

    // Workspace (float units), same 115.2 MiB envelope.
    float* ws    = (float*)d_ws;
    float* gn1_s = ws;                  float* gn1_b = ws + 4096;
    float* gn2_s = ws + 8192;           float* gn2_b = ws + 12288;
    ushort_t* cnb = (ushort_t*)(ws + 16384);     // [8][128][768] bf16
    float* x1    = ws + 489472;         // 4194304 fl; wk_bf borrows it pre-proj
    ushort_t* wk_bf = (ushort_t*)x1;             // [1024][768] bf16
    ushort_t* ts_h = (ushort_t*)(ws + 4683776);  // split activation slot
    ushort_t* ts_l = ts_h + 4194304;
    ushort_t* qt  = (ushort_t*)(ws + 8878080);   // [8][1024][512] bf16
    ushort_t* kt  = qt + 4194304;                // [8][1024][512]
    ushort_t* vn  = kt + 4194304;                // [8][512][1024]
    float*    hb  = ws + 15169536;               // [8][1024][512] fp32
    ushort_t* kct = (ushort_t*)(ws + 19363840);  // [8][128][512]
    ushort_t* vcn = kct + 524288;                // [8][512][128]
    ushort_t* yt  = (ushort_t*)(ws + 8878080);   // [8][1024][2048] bf16 (overlay)
    ushort_t* wq_h = (ushort_t*)(ws + 25655296); // [1536][512] bf16 (hi only)
    ushort_t* wp_h = wq_h + 1572864;             // [512][512]
    ushort_t* w1_h = wp_h + 524288;              // [2048][512]
    ushort_t* w2_h = w1_h + 1048576;             // [512][2048] hi
    ushort_t* w2_l = w2_h + 1048576;             // [512][2048] lo

    // 1) GN1 stats; weight conversions (qkv/proj/ffn1 hi-only; ffn2 split)
    gn_stats_k<<<256, 256, 0, stream>>>(x, gn_w, gn_b, gn1_s, gn1_b);
    wcast_k<<<768, 256, 0, stream>>>(qkv_w, wq_h, 196608);
    wcast_k<<<256, 256, 0, stream>>>(proj_w, wp_h, 65536);
    wcast_k<<<1024, 256, 0, stream>>>(ffn_w1, w1_h, 262144);
    wsplit_k<<<1024, 256, 0, stream>>>(ffn_w2, w2_h, w2_l, 262144);
    wcast_k<<<768, 256, 0, stream>>>(kvc_w, wk_bf, 196608);
    // 2) xt1 = T(GN1(x)) split
    tsplit_k<true><<<dim3(16, 8, 8), 256, 0, stream>>>(x, gn1_s, gn1_b, ts_h, ts_l, 512, 1024);
    // 3) qkv GEMM (VAR=1: Wh*Xh + Wh*Xl): q/k -> qt/kt; v -> vn
    mgemm_k<3, 4, 1><<<dim3(8, 8, 8), 256, 0, stream>>>(
        wq_h, nullptr, ts_h, ts_l, qkv_b, nullptr, nullptr, qt, kt, 1024, 512, 1024);
    mgemm_k<4, 4, 1><<<dim3(8, 4, 8), 256, 0, stream>>>(
        wq_h + (size_t)1024 * 512, nullptr, ts_h, ts_l,
        qkv_b + 1024, nullptr, nullptr, vn, nullptr, 512, 512, 1024);
    // 4) self-attention -> hb [b][t][c]
    mattn_k<false><<<dim3(16, 8, 8), 256, 0, stream>>>(
        qt, kt, vn, hb, nullptr, 1024, 1024,
        (size_t)1024 * 512, (size_t)512 * 1024, 1024);
    // 5) LN(cond) bf16; kvc MFMA -> kct/vcn
    ln_bf_k<<<1024, 256, 0, stream>>>(cond, ln_w, ln_b, cnb);
    kvc_mfma_k<<<dim3(1, 8, 8), 256, 0, stream>>>(wk_bf, cnb, kvc_b, kct, vcn);
    // 6) cross-attention, accumulate into hb
    mattn_k<true><<<dim3(16, 8, 8), 256, 0, stream>>>(
        qt, kct, vcn, hb, cmask, 128, 77,
        (size_t)128 * 512, (size_t)512 * 128, 128);
    // 7) split hb -> ts; proj GEMM (VAR=1, fp32 out + residual)
    wsplit_k<<<1024, 256, 0, stream>>>(hb, ts_h, ts_l, 1048576);
    mgemm_k<1, 4, 1><<<dim3(8, 4, 8), 256, 0, stream>>>(
        wp_h, nullptr, ts_h, ts_l, proj_b, x, x1, nullptr, nullptr, 512, 512, 1024);
    // 8) GN2; x1t split; ffn1 (VAR=1, gelu -> yt plain bf16 transposed);
    //    ffn2 (VAR=2: Wh*y + Wl*y, NF=2 -> 512 blocks)
    gn_stats_k<<<256, 256, 0, stream>>>(x1, ffn_gn_w, ffn_gn_b, gn2_s, gn2_b);
    tsplit_k<true><<<dim3(16, 8, 8), 256, 0, stream>>>(x1, gn2_s, gn2_b, ts_h, ts_l, 512, 1024);
    mgemm_k<2, 4, 1><<<dim3(8, 16, 8), 256, 0, stream>>>(
        w1_h, nullptr, ts_h, ts_l, ffn_b1, nullptr, nullptr, yt, nullptr, 2048, 512, 1024);
    mgemm_k<1, 2, 2><<<dim3(16, 4, 8), 256, 0, stream>>>(
        w2_h, w2_l, yt, nullptr, ffn_b2, x1, (float*)d_out, nullptr, nullptr, 512, 2048, 1024);
}